// Round 11
// baseline (388.443 us; speedup 1.0000x reference)
//
#include <hip/hip_runtime.h>
#include <stdint.h>

// Problem constants
#define N_ENTS  100000
#define N_RELS  16
#define DIM     128
#define NB      4
#define TILE_U  10240           // ushorts per WtT n-tile: 80*16*8
#define NEDGE   640000
#define BATCH   1024
#define NNEG    64
#define BN_EPS  1e-5f
#define BCAP    64              // bucket capacity per node
#define SENTR   0x01000000u     // sentinel record: rel=16 (zero coeff), src=0
#define NPB     32              // nodes per fused block
#define NBLK2   3125            // N_ENTS/NPB exact

// merged k_conv block ranges
#define B_X     0               // [0,6250): x fp32->bf16 (early-exit if bf16)
#define B_CNT   6250            // [6250,6348): zero cnt (98 blocks of uint4)
#define B_TW    6348            // [6348,6428): WtT build from RAW inputs (80 blocks)
#define B_CF    6428            // cf32 table (1 block)
#define B_PAR   6429            // [6429,6440): small param convert (2816 elems)
#define B_GRID  6440

// converted-parameter buffer layout (ushort offsets) — only small params now
#define P_REL    0        // [16][128]
#define P_BSL    2048     // [2][128]
#define P_GAMMA  2304     // [2][128]
#define P_BETA   2560     // [2][128]
#define P_TOTAL  2816

typedef unsigned int uint;
typedef short short8 __attribute__((ext_vector_type(8)));
typedef float f4 __attribute__((ext_vector_type(4)));

__device__ __forceinline__ float bf2f(unsigned short u) {
    return __uint_as_float(((unsigned int)u) << 16);
}
__device__ __forceinline__ float bflo(unsigned int u) { return __uint_as_float(u << 16); }
__device__ __forceinline__ float bfhi(unsigned int u) { return __uint_as_float(u & 0xffff0000u); }
__device__ __forceinline__ unsigned short f2bf(float f) {
    unsigned int x = __float_as_uint(f);
    x += 0x7fffu + ((x >> 16) & 1u);
    return (unsigned short)(x >> 16);
}
__device__ __forceinline__ unsigned int pack2(float a, float b) {
    return (unsigned int)f2bf(a) | ((unsigned int)f2bf(b) << 16);
}

// ---------------- dtype detection (fp32 vs bf16 storage) + stats zero ----------------
__device__ __forceinline__ int bf16_like(unsigned int h) {
    unsigned int m = h & 0x7FFFu;
    return (m == 0u) || (m >= 0x2D00u && m < 0x4400u);
}
__global__ __launch_bounds__(256) void k_detect(const unsigned int* __restrict__ ent,
                                                int* __restrict__ flag,
                                                float* __restrict__ stats) {
    __shared__ int cnt[256];
    unsigned int u = ent[threadIdx.x];
    cnt[threadIdx.x] = bf16_like(u & 0xFFFFu) & bf16_like(u >> 16);
    stats[threadIdx.x] = 0.f;                      // zero stats[512] inline
    stats[256 + threadIdx.x] = 0.f;
    __syncthreads();
    for (int s = 128; s > 0; s >>= 1) {
        if (threadIdx.x < s) cnt[threadIdx.x] += cnt[threadIdx.x + s];
        __syncthreads();
    }
    if (threadIdx.x == 0) flag[0] = (cnt[0] >= 140) ? 1 : 0;
}

// ---------------- merged convert/setup kernel ----------------
// x convert (fp32 path), cnt zero, WtT build (from raw inputs), cf32, small params.
__device__ __forceinline__ unsigned short cvt1(const void* src, int i, int isbf) {
    return isbf ? ((const unsigned short*)src)[i] : f2bf(((const float*)src)[i]);
}
__global__ __launch_bounds__(256) void k_conv(
    const void* __restrict__ src, unsigned short* __restrict__ xrow,
    const void* __restrict__ rtab, const void* __restrict__ bases,
    const void* __restrict__ coeffs, const void* __restrict__ wsl,
    const void* __restrict__ bsl, const void* __restrict__ gamma,
    const void* __restrict__ beta,
    unsigned short* __restrict__ par, unsigned short* __restrict__ WtT,
    float* __restrict__ cf32, int* __restrict__ cnt, const int* __restrict__ flag)
{
    const int b = blockIdx.x;
    const int isbf = flag[0];
    if (b < B_CNT) {                               // ---- x conversion
        if (isbf) return;                          // bf16 input: ent used directly
        const int kc = threadIdx.x >> 4, r = threadIdx.x & 15;
        const int n = b * 16 + r;
        const size_t e0 = (size_t)n * DIM + kc * 8;
        const float4 f0 = *(const float4*)((const float*)src + e0);
        const float4 f1 = *(const float4*)((const float*)src + e0 + 4);
        uint4 w;
        w.x = pack2(f0.x, f0.y); w.y = pack2(f0.z, f0.w);
        w.z = pack2(f1.x, f1.y); w.w = pack2(f1.z, f1.w);
        *(uint4*)(xrow + e0) = w;
        return;
    }
    if (b < B_TW) {                                // ---- zero cnt via uint4 stores
        const int i = (b - B_CNT) * 256 + threadIdx.x;   // uint4 index
        if (i < N_ENTS / 4) {
            uint4 z = {0, 0, 0, 0};
            ((uint4*)cnt)[i] = z;
        }
        return;
    }
    if (b < B_CF) {                                // ---- WtT from RAW wsl/bases
        const int i = (b - B_TW) * 256 + threadIdx.x;    // [0, 20480)
        const int l = i / 10240;
        const int rem = i - l * 10240;
        const int jt2 = rem / 1280;
        const int rem2 = rem - jt2 * 1280;
        const int kc = rem2 >> 4, r = rem2 & 15;
        const int n = jt2 * 16 + r;
        unsigned short v[8];
#pragma unroll
        for (int e = 0; e < 8; ++e) {
            const int k = kc * 8 + e;
            v[e] = (k < DIM)
                ? cvt1(wsl,   l * DIM * DIM + k * DIM + n, isbf)
                : cvt1(bases, l * NB * DIM * DIM + (k - DIM) * DIM + n, isbf);
        }
        *(uint4*)(WtT + (size_t)l * 81920 + (size_t)jt2 * TILE_U + (size_t)kc * 128 + r * 8) = *(uint4*)v;
        return;
    }
    if (b == B_CF) {                               // ---- cf32 [2][17][4], rel=16 -> 0
        const int i = threadIdx.x;
        if (i < 2 * 17 * 4) {
            const int l = i / 68, rem = i - l * 68, r = rem >> 2, bb = rem & 3;
            const int idx = l * N_RELS * NB + r * NB + bb;
            cf32[i] = (r < N_RELS)
                ? (isbf ? bf2f(((const unsigned short*)coeffs)[idx])
                        : ((const float*)coeffs)[idx])
                : 0.f;
        }
        return;
    }
    // ---- small params: rel, bsl, gamma, beta
    const int i = (b - B_PAR) * 256 + threadIdx.x;
    if (i >= P_TOTAL) return;
    unsigned short v;
    if      (i < P_BSL)    v = cvt1(rtab,  i - P_REL,   isbf);
    else if (i < P_GAMMA)  v = cvt1(bsl,   i - P_BSL,   isbf);
    else if (i < P_BETA)   v = cvt1(gamma, i - P_GAMMA, isbf);
    else                   v = cvt1(beta,  i - P_BETA,  isbf);
    par[i] = v;
}

// ---------------- one-kernel bucket CSR: cnt + bucket[n][64] ----------------
__global__ __launch_bounds__(256) void k_fillB(const int* __restrict__ src, const int* __restrict__ dst,
                                               const int* __restrict__ et, int* __restrict__ cnt,
                                               uint* __restrict__ bucket) {
    const int e = blockIdx.x * 256 + threadIdx.x;   // grid exact: NEDGE/256
    const int d = dst[e];
    const int p = atomicAdd(&cnt[d], 1);
    if (p < BCAP) bucket[(size_t)d * BCAP + p] = (uint)src[e] | ((uint)et[e] << 20);
}

// ---------------- FUSED (BN of prev layer) + aggregate + GEMM + epilogue ----------------
// r10-proven base + NEW (r11): 1-deep pr-pipeline. Records/cnt live in LDS (r10), so
// issuing a chain's 16 gathers is VALU-only; ping-pong xwP/xwQ lets chain pr+1's
// gathers fly while chain pr's FMAs run. Per-node tails (j>=1) stay serial (19%/node).
// DO NOT: min-waves 8 (r3 spill), qm=max-of-4 chains (r7), atomic stats (r8). Measured.
__global__ __launch_bounds__(256, 4) void k_fused(
    const uint* __restrict__ bucket, const int* __restrict__ cnt,
    const float* __restrict__ cf, const unsigned short* __restrict__ xin,
    const void* __restrict__ ent, const int* __restrict__ flag, const int lay,
    const float* __restrict__ stp, const unsigned short* __restrict__ gprev,
    const unsigned short* __restrict__ bprev,
    const unsigned short* __restrict__ wtT, const unsigned short* __restrict__ bsl,
    unsigned short* __restrict__ out, float* __restrict__ pstats)
{
    __shared__ unsigned short Ash[NPB * 640];            // 40960 B
    __shared__ __align__(16) uint  bkL[NPB][16];         // 2048 B: first 16 records/node
    __shared__ __align__(16) float cfL[17][4];           // 272 B coeff table
    __shared__ int cntL[NPB];                            // 128 B raw degrees
    const int tid = threadIdx.x;
    const int wave = tid >> 6, lane = tid & 63;
    const int n0 = blockIdx.x * NPB;
    const float inv_n = 1.0f / (float)N_ENTS;

    const unsigned short* __restrict__ xs =
        (lay == 0 && flag[0]) ? (const unsigned short*)ent : xin;
    const int mybase = n0 + wave * 8;

    // ---- phase 0: per-wave LDS staging of bucket records / cnt / coeffs
    {
        const int nd = wave * 8 + (lane >> 3);           // this wave's nodes only
        const int p  = lane & 7;                         // record pair 0..7 (recs 0..15)
        const uint2 rv = *(const uint2*)(bucket + (size_t)(n0 + nd) * BCAP + p * 2);
        *(uint2*)&bkL[nd][p * 2] = rv;
        if (lane < 17) {
            const float4 c4 = *(const float4*)(cf + lane * 4);
            *(float4*)&cfL[lane][0] = c4;
        }
        if (lane < 8) cntL[wave * 8 + lane] = cnt[mybase + lane];   // RAW (deg semantics)
    }

    // per-lane BN coeffs for gather columns {2*lane, 2*lane+1} (identity for lay 0)
    float gnA = 1.f, ofA = 0.f, gnB = 1.f, ofB = 0.f;
    if (lay) {
        const int f0 = lane * 2, f1 = f0 + 1;
        const float mu0 = stp[f0] * inv_n, mu1 = stp[f1] * inv_n;
        const float va0 = stp[DIM + f0] * inv_n - mu0 * mu0;
        const float va1 = stp[DIM + f1] * inv_n - mu1 * mu1;
        gnA = bf2f(gprev[f0]) * rsqrtf(va0 + BN_EPS); ofA = bf2f(bprev[f0]) - mu0 * gnA;
        gnB = bf2f(gprev[f1]) * rsqrtf(va1 + BN_EPS); ofB = bf2f(bprev[f1]) - mu1 * gnB;
    }

    // ---- phase 1: stage self rows into LDS (k 0..127 = 256B/row), swizzled, BN-applied
    {
        const int r = tid >> 3, c = tid & 7;       // 32 rows; chunks c and c+8 (16B each)
        const size_t e0 = (size_t)(n0 + r) * DIM + c * 8;
        uint4 v0 = *(const uint4*)(xs + e0);
        uint4 v1 = *(const uint4*)(xs + e0 + 64);
        if (lay) {
            uint vv[8] = {v0.x, v0.y, v0.z, v0.w, v1.x, v1.y, v1.z, v1.w};
#pragma unroll
            for (int p = 0; p < 8; ++p) {
                const int f0 = c * 8 + (p >> 2) * 64 + (p & 3) * 2;
                const float mu0 = stp[f0] * inv_n, mu1 = stp[f0 + 1] * inv_n;
                const float va0 = stp[DIM + f0] * inv_n - mu0 * mu0;
                const float va1 = stp[DIM + f0 + 1] * inv_n - mu1 * mu1;
                const float g0 = bf2f(gprev[f0]) * rsqrtf(va0 + BN_EPS);
                const float g1 = bf2f(gprev[f0 + 1]) * rsqrtf(va1 + BN_EPS);
                const float o0 = bf2f(bprev[f0]) - mu0 * g0;
                const float o1 = bf2f(bprev[f0 + 1]) - mu1 * g1;
                const float w0 = fmaxf(fmaf(bflo(vv[p]), g0, o0), 0.f);
                const float w1 = fmaxf(fmaf(bfhi(vv[p]), g1, o1), 0.f);
                vv[p] = pack2(w0, w1);
            }
            v0.x = vv[0]; v0.y = vv[1]; v0.z = vv[2]; v0.w = vv[3];
            v1.x = vv[4]; v1.y = vv[5]; v1.z = vv[6]; v1.w = vv[7];
        }
        const int byte0 = (r * 1280 + c * 16) ^ ((r & 7) << 4);
        *(uint4*)((char*)Ash + byte0) = v0;
        *(uint4*)((char*)Ash + byte0 + 128) = v1;   // +128: bit7 only, outside XOR bits 4-6
    }

    // ---- phase 2: PIPELINED gather-aggregate (issue pr+1 while consuming pr)
    const uint* __restrict__ x32 = (const uint*)xs;
    uint xwP[2][8], xwQ[2][8];

    auto issue = [&](int pr, uint (&XW)[2][8]) {
        const int la = wave * 8 + pr * 2;
#pragma unroll
        for (int h = 0; h < 2; ++h) {
            int cn = cntL[la + h]; if (cn > BCAP) cn = BCAP;
#pragma unroll
            for (int s = 0; s < 8; ++s) {
                uint rr = bkL[la + h][s];
                if (s >= cn) rr = SENTR;             // tail mask: rel=16, src=0
                XW[h][s] = x32[(size_t)(rr & 0xFFFFFu) * 64 + lane];
            }
        }
    };

    auto consume = [&](int pr, uint (&XW)[2][8]) {
        const int la = wave * 8 + pr * 2;
        const int na = n0 + la;
        int ca = cntL[la];     if (ca > BCAP) ca = BCAP;
        int cb = cntL[la + 1]; if (cb > BCAP) cb = BCAP;
        float aLo[2][NB] = {{0.f,0.f,0.f,0.f},{0.f,0.f,0.f,0.f}};
        float aHi[2][NB] = {{0.f,0.f,0.f,0.f},{0.f,0.f,0.f,0.f}};
        // j=0: consume prefetched gathers (unconditional; sentinel coeffs are zero)
#pragma unroll
        for (int h = 0; h < 2; ++h) {
            const int cn = h ? cb : ca;
#pragma unroll
            for (int s = 0; s < 8; ++s) {
                const int rel = (s >= cn) ? 16 : (int)(bkL[la + h][s] >> 20);
                const float4 cc = *(const float4*)&cfL[rel][0];
                float xl, xh;
                if (lay) {
                    xl = fmaxf(fmaf(bflo(XW[h][s]), gnA, ofA), 0.f);
                    xh = fmaxf(fmaf(bfhi(XW[h][s]), gnB, ofB), 0.f);
                } else {
                    xl = bflo(XW[h][s]);
                    xh = bfhi(XW[h][s]);
                }
                aLo[h][0] = fmaf(cc.x, xl, aLo[h][0]);
                aHi[h][0] = fmaf(cc.x, xh, aHi[h][0]);
                aLo[h][1] = fmaf(cc.y, xl, aLo[h][1]);
                aHi[h][1] = fmaf(cc.y, xh, aHi[h][1]);
                aLo[h][2] = fmaf(cc.z, xl, aLo[h][2]);
                aHi[h][2] = fmaf(cc.z, xh, aHi[h][2]);
                aLo[h][3] = fmaf(cc.w, xl, aLo[h][3]);
                aHi[h][3] = fmaf(cc.w, xh, aHi[h][3]);
            }
        }
        // tail j>=1: per-node serial (P(deg>8)~19%); j=1 recs from LDS, j>=2 global
#pragma unroll
        for (int h = 0; h < 2; ++h) {
            const int cn = h ? cb : ca;
            const int q = (cn + 7) >> 3;
            const uint4* __restrict__ bkg = (const uint4*)(bucket + (size_t)(na + h) * BCAP);
            for (int j = 1; j < q; ++j) {
                const int b8 = j * 8;
                uint rec[8], xw[8];
                if (j < 2) {
#pragma unroll
                    for (int s = 0; s < 8; ++s) rec[s] = bkL[la + h][b8 + s];
                } else {
                    const uint4 r0 = bkg[j * 2];
                    const uint4 r1 = bkg[j * 2 + 1];
                    rec[0] = r0.x; rec[1] = r0.y; rec[2] = r0.z; rec[3] = r0.w;
                    rec[4] = r1.x; rec[5] = r1.y; rec[6] = r1.z; rec[7] = r1.w;
                }
#pragma unroll
                for (int s = 0; s < 8; ++s) {
                    uint rr = rec[s];
                    if (b8 + s >= cn) rr = SENTR;
                    rec[s] = rr;
                    xw[s] = x32[(size_t)(rr & 0xFFFFFu) * 64 + lane];
                }
#pragma unroll
                for (int s = 0; s < 8; ++s) {
                    const int rel = (int)(rec[s] >> 20);
                    const float4 cc = *(const float4*)&cfL[rel][0];
                    float xl, xh;
                    if (lay) {
                        xl = fmaxf(fmaf(bflo(xw[s]), gnA, ofA), 0.f);
                        xh = fmaxf(fmaf(bfhi(xw[s]), gnB, ofB), 0.f);
                    } else {
                        xl = bflo(xw[s]);
                        xh = bfhi(xw[s]);
                    }
                    aLo[h][0] = fmaf(cc.x, xl, aLo[h][0]);
                    aHi[h][0] = fmaf(cc.x, xh, aHi[h][0]);
                    aLo[h][1] = fmaf(cc.y, xl, aLo[h][1]);
                    aHi[h][1] = fmaf(cc.y, xh, aHi[h][1]);
                    aLo[h][2] = fmaf(cc.z, xl, aLo[h][2]);
                    aHi[h][2] = fmaf(cc.z, xh, aHi[h][2]);
                    aLo[h][3] = fmaf(cc.w, xl, aLo[h][3]);
                    aHi[h][3] = fmaf(cc.w, xh, aHi[h][3]);
                }
            }
        }
        // LDS write of basis-aggregate columns
#pragma unroll
        for (int h = 0; h < 2; ++h) {
            const int ra = la + h;
            const int swz = (ra & 7) << 4;
#pragma unroll
            for (int b = 0; b < NB; ++b) {
                const int byte = (ra * 1280 + 256 + b * 256 + lane * 4) ^ swz;
                *(uint*)((char*)Ash + byte) = pack2(aLo[h][b], aHi[h][b]);
            }
        }
    };

    issue(0, xwP);
    issue(1, xwQ); consume(0, xwP);
    issue(2, xwP); consume(1, xwQ);
    issue(3, xwQ); consume(2, xwP);
    consume(3, xwQ);

    // ---- phase 3: MFMA. wave w: m-tiles {0,1} x n-tiles {2w,2w+1}, K=640 (20 steps)
    const int quad = lane >> 4, l16 = lane & 15;
    f4 acc[2][2];
#pragma unroll
    for (int i = 0; i < 2; ++i)
#pragma unroll
        for (int j = 0; j < 2; ++j)
#pragma unroll
            for (int r = 0; r < 4; ++r) acc[i][j][r] = 0.f;

    const unsigned short* __restrict__ pB0 = wtT + (size_t)(2 * wave) * TILE_U + quad * 128 + l16 * 8;
    const unsigned short* __restrict__ pB1 = pB0 + TILE_U;
    const char* Ab = (const char*)Ash;
    const int swz = (l16 & 7) << 4;
    // even/odd ks bases: XOR touches bits 4-6 and ks*64 carries bit 6 -> two bases
    const int b0e = (l16 * 1280 + quad * 16) ^ swz;
    const int b0o = (l16 * 1280 + 64 + quad * 16) ^ swz;
    const int b1e = ((l16 + 16) * 1280 + quad * 16) ^ swz;
    const int b1o = ((l16 + 16) * 1280 + 64 + quad * 16) ^ swz;

    short8 xa0, xa1, xb0, xb1, ya0, ya1, yb0, yb1;
#define FLDA(P, s) \
    P##a0 = *(const short8*)(Ab + (((s) & 1) ? b0o : b0e) + ((s) >> 1) * 128); \
    P##a1 = *(const short8*)(Ab + (((s) & 1) ? b1o : b1e) + ((s) >> 1) * 128);
#define FLDB(P, s) \
    P##b0 = *(const short8*)(pB0 + (s) * 512); \
    P##b1 = *(const short8*)(pB1 + (s) * 512);
#define FLD(P, s) FLDA(P, s) FLDB(P, s)
#define FMM(P) \
    acc[0][0] = __builtin_amdgcn_mfma_f32_16x16x32_bf16(P##a0, P##b0, acc[0][0], 0, 0, 0); \
    acc[0][1] = __builtin_amdgcn_mfma_f32_16x16x32_bf16(P##a0, P##b1, acc[0][1], 0, 0, 0); \
    acc[1][0] = __builtin_amdgcn_mfma_f32_16x16x32_bf16(P##a1, P##b0, acc[1][0], 0, 0, 0); \
    acc[1][1] = __builtin_amdgcn_mfma_f32_16x16x32_bf16(P##a1, P##b1, acc[1][1], 0, 0, 0);

    // B loads are global (no LDS dependency): issue before the barrier
    FLDB(x, 0) FLDB(y, 1)
    __syncthreads();
    FLDA(x, 0) FLDA(y, 1)
    FMM(x) FLD(x, 2)
    FMM(y) FLD(y, 3)
    FMM(x) FLD(x, 4)
    FMM(y) FLD(y, 5)
    FMM(x) FLD(x, 6)
    FMM(y) FLD(y, 7)
    FMM(x) FLD(x, 8)
    FMM(y) FLD(y, 9)
    FMM(x) FLD(x, 10)
    FMM(y) FLD(y, 11)
    FMM(x) FLD(x, 12)
    FMM(y) FLD(y, 13)
    FMM(x) FLD(x, 14)
    FMM(y) FLD(y, 15)
    FMM(x) FLD(x, 16)
    FMM(y) FLD(y, 17)
    FMM(x) FLD(x, 18)
    FMM(y) FLD(y, 19)
    FMM(x)
    FMM(y)
#undef FLDA
#undef FLDB
#undef FLD
#undef FMM

    // ---- epilogue: o = (acc + bias)/deg, bf16 store, per-block BN partial stats
    // cntL valid across waves here: phase-3 __syncthreads() ordered phase-0 writes.
    float ssum[2] = {0.f, 0.f}, sssq[2] = {0.f, 0.f};
#pragma unroll
    for (int m = 0; m < 2; ++m) {
#pragma unroll
        for (int r = 0; r < 4; ++r) {
            const int lrow = m * 16 + quad * 4 + r;
            const int row = n0 + lrow;                 // always < N_ENTS (3125*32 exact)
            const float rdeg = 1.0f / fmaxf((float)cntL[lrow], 1.0f);
#pragma unroll
            for (int n = 0; n < 2; ++n) {
                const int col = (2 * wave + n) * 16 + l16;
                const float o = (acc[m][n][r] + bf2f(bsl[col])) * rdeg;
                out[(size_t)row * DIM + col] = f2bf(o);
                ssum[n] += o;
                sssq[n] += o * o;
            }
        }
    }
#pragma unroll
    for (int n = 0; n < 2; ++n) {
        float s = ssum[n], q2 = sssq[n];
        s += __shfl_xor(s, 16, 64);  s += __shfl_xor(s, 32, 64);
        q2 += __shfl_xor(q2, 16, 64); q2 += __shfl_xor(q2, 32, 64);
        if (quad == 0) {
            const int col = (2 * wave + n) * 16 + l16;
            pstats[(size_t)blockIdx.x * 256 + col] = s;
            pstats[(size_t)blockIdx.x * 256 + 128 + col] = q2;
        }
    }
}

// ---------------- reduce per-block stats -> st[256] ----------------
__global__ __launch_bounds__(256) void k_stats(const float* __restrict__ pstats,
                                               float* __restrict__ st) {
    const int o = threadIdx.x;
    const int b0 = blockIdx.x * 25;                // grid 125: 125*25 = 3125 exact
    float s = 0.f;
    for (int b = b0; b < b0 + 25; ++b)
        s += pstats[(size_t)b * 256 + o];
    atomicAdd(&st[o], s);
}

// ---------------- fused scoring: one wave per sample, hr cached, 8-deep prefetch ----------------
__global__ __launch_bounds__(256) void k_score(
    const int* __restrict__ head, const int* __restrict__ rel,
    const int* __restrict__ tail, const int* __restrict__ negi,
    const unsigned short* __restrict__ emb, const unsigned short* __restrict__ rtab,
    const float* __restrict__ st1, const unsigned short* __restrict__ gm1,
    const unsigned short* __restrict__ bt1,
    void* __restrict__ outp, const int* __restrict__ flag)
{
    const int wave = threadIdx.x >> 6, lane = threadIdx.x & 63;
    const int i = blockIdx.x * 4 + wave;   // grid exact: BATCH/4 = 256
    const float inv_n = 1.0f / (float)N_ENTS;
    const int f0 = lane * 2, f1 = f0 + 1;
    const float mu0 = st1[f0] * inv_n, mu1 = st1[f1] * inv_n;
    const float va0 = st1[DIM + f0] * inv_n - mu0 * mu0;
    const float va1 = st1[DIM + f1] * inv_n - mu1 * mu1;
    const float g0 = bf2f(gm1[f0]) * rsqrtf(va0 + BN_EPS);
    const float g1 = bf2f(gm1[f1]) * rsqrtf(va1 + BN_EPS);
    const float o0 = bf2f(bt1[f0]) - mu0 * g0;
    const float o1 = bf2f(bt1[f1]) - mu1 * g1;
    const int isbf = flag[0];

    const uint* __restrict__ x32 = (const uint*)emb;
    const uint hv = x32[(size_t)head[i] * 64 + lane];
    const uint rv = ((const uint*)rtab)[(size_t)rel[i] * 64 + lane];
    const float hr0 = fmaxf(fmaf(bflo(hv), g0, o0), 0.f) + bflo(rv);
    const float hr1 = fmaxf(fmaf(bfhi(hv), g1, o1), 0.f) + bfhi(rv);

    // neg indices: one coalesced load, lane l holds negi[i*64+l]
    const int tIdx = negi[i * 64 + lane];
    const uint tvPos = x32[(size_t)tail[i] * 64 + lane];

    auto score1 = [&](uint tvv, int oidx) {
        const float t0 = fmaxf(fmaf(bflo(tvv), g0, o0), 0.f);
        const float t1 = fmaxf(fmaf(bfhi(tvv), g1, o1), 0.f);
        const float d0 = hr0 - t0, d1 = hr1 - t1;
        float s = d0 * d0 + d1 * d1;
#pragma unroll
        for (int m = 32; m >= 1; m >>= 1) s += __shfl_xor(s, m, 64);
        if (lane == 0) {
            const float v = -sqrtf(s);
            if (isbf) ((unsigned short*)outp)[oidx] = f2bf(v);
            else      ((float*)outp)[oidx] = v;
        }
    };

    score1(tvPos, i);                                 // pos score

    // negs: 8 groups of 8 with 1-group lookahead (gathers overlap scoring)
    uint a[8], b[8];
#pragma unroll
    for (int k = 0; k < 8; ++k)
        a[k] = x32[(size_t)__shfl(tIdx, k, 64) * 64 + lane];
#pragma unroll
    for (int g = 0; g < 8; ++g) {
        if (g < 7) {
#pragma unroll
            for (int k = 0; k < 8; ++k) {
                const uint v = x32[(size_t)__shfl(tIdx, (g + 1) * 8 + k, 64) * 64 + lane];
                if (g & 1) a[k] = v; else b[k] = v;
            }
        }
#pragma unroll
        for (int k = 0; k < 8; ++k)
            score1((g & 1) ? b[k] : a[k], BATCH + i * 64 + g * 8 + k);
    }
}

extern "C" void kernel_launch(void* const* d_in, const int* in_sizes, int n_in,
                              void* d_out, int out_size, void* d_ws, size_t ws_size,
                              hipStream_t stream)
{
    const int* head = (const int*)d_in[0];
    const int* rel  = (const int*)d_in[1];
    const int* tail = (const int*)d_in[2];
    const int* negi = (const int*)d_in[3];
    const int* eidx = (const int*)d_in[4];
    const int* etyp = (const int*)d_in[5];
    const void* ent_tab = d_in[6];
    const void* rtab_in = d_in[7];
    const void* bases_in = d_in[8];
    const void* coeffs_in = d_in[9];
    const void* wsl_in = d_in[10];
    const void* bsl_in = d_in[11];
    const void* gamma_in = d_in[12];
    const void* beta_in = d_in[13];

    char* ws = (char*)d_ws;
    size_t off = 0;
    auto alloc = [&](size_t bytes) -> char* {
        char* p = ws + off;
        off += (bytes + 511) & ~(size_t)511;
        return p;
    };
    int* flag            = (int*)alloc(4);
    int* cnt             = (int*)alloc((size_t)N_ENTS * 4);
    uint* bucket         = (uint*)alloc((size_t)N_ENTS * BCAP * 4);             // 25.6 MB
    unsigned short* xrow = (unsigned short*)alloc((size_t)N_ENTS * DIM * 2);    // fp32-input path only
    unsigned short* outA = (unsigned short*)alloc((size_t)N_ENTS * DIM * 2);    // layer-0 raw out
    unsigned short* outB = (unsigned short*)alloc((size_t)N_ENTS * DIM * 2);    // layer-1 raw out
    unsigned short* par  = (unsigned short*)alloc((size_t)P_TOTAL * 2);
    unsigned short* WtT  = (unsigned short*)alloc((size_t)2 * 81920 * 2);
    float* cf32          = (float*)alloc((size_t)2 * 17 * 4 * 4);
    float* pstats        = (float*)alloc((size_t)NBLK2 * 256 * 4);              // 3.2 MB
    float* stats         = (float*)alloc(2 * 2 * DIM * 4);
    (void)ws_size; (void)in_sizes; (void)n_in; (void)out_size;

    const int* esrc = eidx;
    const int* edst = eidx + NEDGE;

    // 8 dispatches: detect(+stats zero), conv(+WtT+cf32+cnt zero+params),
    // fillB, fused0, stats0, fused1, stats1, score.
    k_detect<<<1, 256, 0, stream>>>((const unsigned int*)ent_tab, flag, stats);

    k_conv<<<B_GRID, 256, 0, stream>>>(
        ent_tab, xrow, rtab_in, bases_in, coeffs_in, wsl_in, bsl_in, gamma_in, beta_in,
        par, WtT, cf32, cnt, flag);

    k_fillB<<<NEDGE / 256, 256, 0, stream>>>(esrc, edst, etyp, cnt, bucket);

    // layer 0 (no BN on input)
    k_fused<<<NBLK2, 256, 0, stream>>>(
        bucket, cnt, cf32, xrow, ent_tab, flag, 0,
        stats, par + P_GAMMA, par + P_BETA,          // unused at lay 0
        WtT, par + P_BSL, outA, pstats);
    k_stats<<<125, 256, 0, stream>>>(pstats, stats);

    // layer 1 (BN0+ReLU fused on the fly)
    k_fused<<<NBLK2, 256, 0, stream>>>(
        bucket, cnt, cf32 + 68, outA, ent_tab, flag, 1,
        stats, par + P_GAMMA, par + P_BETA,
        WtT + 81920, par + P_BSL + DIM, outB, pstats);
    k_stats<<<125, 256, 0, stream>>>(pstats, stats + 2 * DIM);

    k_score<<<BATCH / 4, 256, 0, stream>>>(
        head, rel, tail, negi, outB, par + P_REL,
        stats + 2 * DIM, par + P_GAMMA + DIM, par + P_BETA + DIM,
        d_out, flag);
}

// Round 12
// 337.616 us; speedup vs baseline: 1.1505x; 1.1505x over previous
//
#include <hip/hip_runtime.h>
#include <stdint.h>

// Problem constants
#define N_ENTS  100000
#define N_RELS  16
#define DIM     128
#define NB      4
#define TILE_U  10240           // ushorts per WtT n-tile: 80*16*8
#define NEDGE   640000
#define BATCH   1024
#define NNEG    64
#define BN_EPS  1e-5f
#define BCAP    64              // bucket capacity per node
#define SENTR   0x01000000u     // sentinel record: rel=16 (zero coeff), src=0
#define NPB     32              // nodes per fused block
#define NBLK2   3125            // N_ENTS/NPB exact

// merged k_conv block ranges
#define B_X     0               // [0,6250): x fp32->bf16 (early-exit if bf16)
#define B_CNT   6250            // [6250,6348): zero cnt (98 blocks of uint4)
#define B_TW    6348            // [6348,6428): WtT build from RAW inputs (80 blocks)
#define B_CF    6428            // cf32 table (1 block)
#define B_PAR   6429            // [6429,6440): small param convert (2816 elems)
#define B_GRID  6440

// converted-parameter buffer layout (ushort offsets) — only small params now
#define P_REL    0        // [16][128]
#define P_BSL    2048     // [2][128]
#define P_GAMMA  2304     // [2][128]
#define P_BETA   2560     // [2][128]
#define P_TOTAL  2816

typedef unsigned int uint;
typedef short short8 __attribute__((ext_vector_type(8)));
typedef float f4 __attribute__((ext_vector_type(4)));

__device__ __forceinline__ float bf2f(unsigned short u) {
    return __uint_as_float(((unsigned int)u) << 16);
}
__device__ __forceinline__ float bflo(unsigned int u) { return __uint_as_float(u << 16); }
__device__ __forceinline__ float bfhi(unsigned int u) { return __uint_as_float(u & 0xffff0000u); }
__device__ __forceinline__ unsigned short f2bf(float f) {
    unsigned int x = __float_as_uint(f);
    x += 0x7fffu + ((x >> 16) & 1u);
    return (unsigned short)(x >> 16);
}
__device__ __forceinline__ unsigned int pack2(float a, float b) {
    return (unsigned int)f2bf(a) | ((unsigned int)f2bf(b) << 16);
}

// ---------------- dtype detection (fp32 vs bf16 storage) + stats zero ----------------
__device__ __forceinline__ int bf16_like(unsigned int h) {
    unsigned int m = h & 0x7FFFu;
    return (m == 0u) || (m >= 0x2D00u && m < 0x4400u);
}
__global__ __launch_bounds__(256) void k_detect(const unsigned int* __restrict__ ent,
                                                int* __restrict__ flag,
                                                float* __restrict__ stats) {
    __shared__ int cnt[256];
    unsigned int u = ent[threadIdx.x];
    cnt[threadIdx.x] = bf16_like(u & 0xFFFFu) & bf16_like(u >> 16);
    stats[threadIdx.x] = 0.f;                      // zero stats[512] inline
    stats[256 + threadIdx.x] = 0.f;
    __syncthreads();
    for (int s = 128; s > 0; s >>= 1) {
        if (threadIdx.x < s) cnt[threadIdx.x] += cnt[threadIdx.x + s];
        __syncthreads();
    }
    if (threadIdx.x == 0) flag[0] = (cnt[0] >= 140) ? 1 : 0;
}

// ---------------- merged convert/setup kernel ----------------
// x convert (fp32 path), cnt zero, WtT build (from raw inputs), cf32, small params.
__device__ __forceinline__ unsigned short cvt1(const void* src, int i, int isbf) {
    return isbf ? ((const unsigned short*)src)[i] : f2bf(((const float*)src)[i]);
}
__global__ __launch_bounds__(256) void k_conv(
    const void* __restrict__ src, unsigned short* __restrict__ xrow,
    const void* __restrict__ rtab, const void* __restrict__ bases,
    const void* __restrict__ coeffs, const void* __restrict__ wsl,
    const void* __restrict__ bsl, const void* __restrict__ gamma,
    const void* __restrict__ beta,
    unsigned short* __restrict__ par, unsigned short* __restrict__ WtT,
    float* __restrict__ cf32, int* __restrict__ cnt, const int* __restrict__ flag)
{
    const int b = blockIdx.x;
    const int isbf = flag[0];
    if (b < B_CNT) {                               // ---- x conversion
        if (isbf) return;                          // bf16 input: ent used directly
        const int kc = threadIdx.x >> 4, r = threadIdx.x & 15;
        const int n = b * 16 + r;
        const size_t e0 = (size_t)n * DIM + kc * 8;
        const float4 f0 = *(const float4*)((const float*)src + e0);
        const float4 f1 = *(const float4*)((const float*)src + e0 + 4);
        uint4 w;
        w.x = pack2(f0.x, f0.y); w.y = pack2(f0.z, f0.w);
        w.z = pack2(f1.x, f1.y); w.w = pack2(f1.z, f1.w);
        *(uint4*)(xrow + e0) = w;
        return;
    }
    if (b < B_TW) {                                // ---- zero cnt via uint4 stores
        const int i = (b - B_CNT) * 256 + threadIdx.x;   // uint4 index
        if (i < N_ENTS / 4) {
            uint4 z = {0, 0, 0, 0};
            ((uint4*)cnt)[i] = z;
        }
        return;
    }
    if (b < B_CF) {                                // ---- WtT from RAW wsl/bases
        const int i = (b - B_TW) * 256 + threadIdx.x;    // [0, 20480)
        const int l = i / 10240;
        const int rem = i - l * 10240;
        const int jt2 = rem / 1280;
        const int rem2 = rem - jt2 * 1280;
        const int kc = rem2 >> 4, r = rem2 & 15;
        const int n = jt2 * 16 + r;
        unsigned short v[8];
#pragma unroll
        for (int e = 0; e < 8; ++e) {
            const int k = kc * 8 + e;
            v[e] = (k < DIM)
                ? cvt1(wsl,   l * DIM * DIM + k * DIM + n, isbf)
                : cvt1(bases, l * NB * DIM * DIM + (k - DIM) * DIM + n, isbf);
        }
        *(uint4*)(WtT + (size_t)l * 81920 + (size_t)jt2 * TILE_U + (size_t)kc * 128 + r * 8) = *(uint4*)v;
        return;
    }
    if (b == B_CF) {                               // ---- cf32 [2][17][4], rel=16 -> 0
        const int i = threadIdx.x;
        if (i < 2 * 17 * 4) {
            const int l = i / 68, rem = i - l * 68, r = rem >> 2, bb = rem & 3;
            const int idx = l * N_RELS * NB + r * NB + bb;
            cf32[i] = (r < N_RELS)
                ? (isbf ? bf2f(((const unsigned short*)coeffs)[idx])
                        : ((const float*)coeffs)[idx])
                : 0.f;
        }
        return;
    }
    // ---- small params: rel, bsl, gamma, beta
    const int i = (b - B_PAR) * 256 + threadIdx.x;
    if (i >= P_TOTAL) return;
    unsigned short v;
    if      (i < P_BSL)    v = cvt1(rtab,  i - P_REL,   isbf);
    else if (i < P_GAMMA)  v = cvt1(bsl,   i - P_BSL,   isbf);
    else if (i < P_BETA)   v = cvt1(gamma, i - P_GAMMA, isbf);
    else                   v = cvt1(beta,  i - P_BETA,  isbf);
    par[i] = v;
}

// ---------------- one-kernel bucket CSR: cnt + bucket[n][64] ----------------
__global__ __launch_bounds__(256) void k_fillB(const int* __restrict__ src, const int* __restrict__ dst,
                                               const int* __restrict__ et, int* __restrict__ cnt,
                                               uint* __restrict__ bucket) {
    const int e = blockIdx.x * 256 + threadIdx.x;   // grid exact: NEDGE/256
    const int d = dst[e];
    const int p = atomicAdd(&cnt[d], 1);
    if (p < BCAP) bucket[(size_t)d * BCAP + p] = (uint)src[e] | ((uint)et[e] << 20);
}

// ---------------- FUSED (BN of prev layer) + aggregate + GEMM + epilogue ----------------
// r10-PROVEN kernel (94.8 us/layer, VGPR 72): 256 thr (4 waves), NPB=32, runtime lay,
// pstats epilogue. Bucket records (first 16/node), cnt, coeffs staged in LDS per-wave.
// DO NOT TOUCH phase 2: r7 (4-chain, VGPR 100), r8 (atomic stats), r11 (ping-pong
// xwP/xwQ, VGPR 96) all regressed — register-held gather pipelining loses occupancy.
__global__ __launch_bounds__(256, 4) void k_fused(
    const uint* __restrict__ bucket, const int* __restrict__ cnt,
    const float* __restrict__ cf, const unsigned short* __restrict__ xin,
    const void* __restrict__ ent, const int* __restrict__ flag, const int lay,
    const float* __restrict__ stp, const unsigned short* __restrict__ gprev,
    const unsigned short* __restrict__ bprev,
    const unsigned short* __restrict__ wtT, const unsigned short* __restrict__ bsl,
    unsigned short* __restrict__ out, float* __restrict__ pstats)
{
    __shared__ unsigned short Ash[NPB * 640];            // 40960 B
    __shared__ __align__(16) uint  bkL[NPB][16];         // 2048 B: first 16 records/node
    __shared__ __align__(16) float cfL[17][4];           // 272 B coeff table
    __shared__ int cntL[NPB];                            // 128 B raw degrees
    const int tid = threadIdx.x;
    const int wave = tid >> 6, lane = tid & 63;
    const int n0 = blockIdx.x * NPB;
    const float inv_n = 1.0f / (float)N_ENTS;

    const unsigned short* __restrict__ xs =
        (lay == 0 && flag[0]) ? (const unsigned short*)ent : xin;
    const int mybase = n0 + wave * 8;

    // ---- phase 0: per-wave LDS staging of bucket records / cnt / coeffs
    {
        const int nd = wave * 8 + (lane >> 3);           // this wave's nodes only
        const int p  = lane & 7;                         // record pair 0..7 (recs 0..15)
        const uint2 rv = *(const uint2*)(bucket + (size_t)(n0 + nd) * BCAP + p * 2);
        *(uint2*)&bkL[nd][p * 2] = rv;
        if (lane < 17) {
            const float4 c4 = *(const float4*)(cf + lane * 4);
            *(float4*)&cfL[lane][0] = c4;
        }
        if (lane < 8) cntL[wave * 8 + lane] = cnt[mybase + lane];   // RAW (deg semantics)
    }

    // per-lane BN coeffs for gather columns {2*lane, 2*lane+1} (identity for lay 0)
    float gnA = 1.f, ofA = 0.f, gnB = 1.f, ofB = 0.f;
    if (lay) {
        const int f0 = lane * 2, f1 = f0 + 1;
        const float mu0 = stp[f0] * inv_n, mu1 = stp[f1] * inv_n;
        const float va0 = stp[DIM + f0] * inv_n - mu0 * mu0;
        const float va1 = stp[DIM + f1] * inv_n - mu1 * mu1;
        gnA = bf2f(gprev[f0]) * rsqrtf(va0 + BN_EPS); ofA = bf2f(bprev[f0]) - mu0 * gnA;
        gnB = bf2f(gprev[f1]) * rsqrtf(va1 + BN_EPS); ofB = bf2f(bprev[f1]) - mu1 * gnB;
    }

    // ---- phase 1: stage self rows into LDS (k 0..127 = 256B/row), swizzled, BN-applied
    {
        const int r = tid >> 3, c = tid & 7;       // 32 rows; chunks c and c+8 (16B each)
        const size_t e0 = (size_t)(n0 + r) * DIM + c * 8;
        uint4 v0 = *(const uint4*)(xs + e0);
        uint4 v1 = *(const uint4*)(xs + e0 + 64);
        if (lay) {
            uint vv[8] = {v0.x, v0.y, v0.z, v0.w, v1.x, v1.y, v1.z, v1.w};
#pragma unroll
            for (int p = 0; p < 8; ++p) {
                const int f0 = c * 8 + (p >> 2) * 64 + (p & 3) * 2;
                const float mu0 = stp[f0] * inv_n, mu1 = stp[f0 + 1] * inv_n;
                const float va0 = stp[DIM + f0] * inv_n - mu0 * mu0;
                const float va1 = stp[DIM + f0 + 1] * inv_n - mu1 * mu1;
                const float g0 = bf2f(gprev[f0]) * rsqrtf(va0 + BN_EPS);
                const float g1 = bf2f(gprev[f0 + 1]) * rsqrtf(va1 + BN_EPS);
                const float o0 = bf2f(bprev[f0]) - mu0 * g0;
                const float o1 = bf2f(bprev[f0 + 1]) - mu1 * g1;
                const float w0 = fmaxf(fmaf(bflo(vv[p]), g0, o0), 0.f);
                const float w1 = fmaxf(fmaf(bfhi(vv[p]), g1, o1), 0.f);
                vv[p] = pack2(w0, w1);
            }
            v0.x = vv[0]; v0.y = vv[1]; v0.z = vv[2]; v0.w = vv[3];
            v1.x = vv[4]; v1.y = vv[5]; v1.z = vv[6]; v1.w = vv[7];
        }
        const int byte0 = (r * 1280 + c * 16) ^ ((r & 7) << 4);
        *(uint4*)((char*)Ash + byte0) = v0;
        *(uint4*)((char*)Ash + byte0 + 128) = v1;   // +128: bit7 only, outside XOR bits 4-6
    }

    // ---- phase 2: gather-aggregate; records from LDS (broadcast), 2-node interleave
    const uint* __restrict__ x32 = (const uint*)xs;
    for (int pr = 0; pr < 4; ++pr) {
        const int la = wave * 8 + pr * 2;
        const int na = mybase + pr * 2;
        int ca = cntL[la];     if (ca > BCAP) ca = BCAP;
        int cb = cntL[la + 1]; if (cb > BCAP) cb = BCAP;
        const int qm = ((ca > cb ? ca : cb) + 7) >> 3;
        float aLo[2][NB] = {{0.f,0.f,0.f,0.f},{0.f,0.f,0.f,0.f}};
        float aHi[2][NB] = {{0.f,0.f,0.f,0.f},{0.f,0.f,0.f,0.f}};
        const uint4* __restrict__ bkg = (const uint4*)(bucket + (size_t)na * BCAP);
        for (int j = 0; j < qm; ++j) {
            uint rec[2][8];
            uint xw[2][8];
            const int b8 = j * 8;
#pragma unroll
            for (int h = 0; h < 2; ++h) {
                const int cn = h ? cb : ca;
                if (b8 < cn) {
                    if (j < 2) {                         // records 0..15: LDS broadcast
#pragma unroll
                        for (int s = 0; s < 8; ++s) rec[h][s] = bkL[la + h][b8 + s];
                    } else {                             // rare: records 16+ from global
                        const uint4 r0 = bkg[h * 16 + j * 2];
                        const uint4 r1 = bkg[h * 16 + j * 2 + 1];
                        rec[h][0] = r0.x; rec[h][1] = r0.y; rec[h][2] = r0.z; rec[h][3] = r0.w;
                        rec[h][4] = r1.x; rec[h][5] = r1.y; rec[h][6] = r1.z; rec[h][7] = r1.w;
                    }
#pragma unroll
                    for (int s = 0; s < 8; ++s) {
                        uint rr = rec[h][s];
                        if (b8 + s >= cn) rr = SENTR;    // tail mask: rel=16, src=0
                        rec[h][s] = rr;
                        xw[h][s] = x32[(size_t)(rr & 0xFFFFFu) * 64 + lane];
                    }
                }
            }
#pragma unroll
            for (int h = 0; h < 2; ++h) {
                const int cn = h ? cb : ca;
                if (b8 < cn) {
#pragma unroll
                    for (int s = 0; s < 8; ++s) {
                        const int rel = (int)(rec[h][s] >> 20);   // 16 -> zero coeffs
                        const float4 cc = *(const float4*)&cfL[rel][0];  // LDS broadcast
                        float xl, xh;
                        if (lay) {
                            xl = fmaxf(fmaf(bflo(xw[h][s]), gnA, ofA), 0.f);
                            xh = fmaxf(fmaf(bfhi(xw[h][s]), gnB, ofB), 0.f);
                        } else {
                            xl = bflo(xw[h][s]);
                            xh = bfhi(xw[h][s]);
                        }
                        aLo[h][0] = fmaf(cc.x, xl, aLo[h][0]);
                        aHi[h][0] = fmaf(cc.x, xh, aHi[h][0]);
                        aLo[h][1] = fmaf(cc.y, xl, aLo[h][1]);
                        aHi[h][1] = fmaf(cc.y, xh, aHi[h][1]);
                        aLo[h][2] = fmaf(cc.z, xl, aLo[h][2]);
                        aHi[h][2] = fmaf(cc.z, xh, aHi[h][2]);
                        aLo[h][3] = fmaf(cc.w, xl, aLo[h][3]);
                        aHi[h][3] = fmaf(cc.w, xh, aHi[h][3]);
                    }
                }
            }
        }
#pragma unroll
        for (int h = 0; h < 2; ++h) {
            const int ra = wave * 8 + pr * 2 + h;
            const int swz = (ra & 7) << 4;
#pragma unroll
            for (int b = 0; b < NB; ++b) {
                // A[ra][128 + b*128 + 2*lane .. +1]  (bank-conflict-free: lane*4 stride)
                const int byte = (ra * 1280 + 256 + b * 256 + lane * 4) ^ swz;
                *(uint*)((char*)Ash + byte) = pack2(aLo[h][b], aHi[h][b]);
            }
        }
    }

    // ---- phase 3: MFMA. wave w: m-tiles {0,1} x n-tiles {2w,2w+1}, K=640 (20 steps)
    const int quad = lane >> 4, l16 = lane & 15;
    f4 acc[2][2];
#pragma unroll
    for (int i = 0; i < 2; ++i)
#pragma unroll
        for (int j = 0; j < 2; ++j)
#pragma unroll
            for (int r = 0; r < 4; ++r) acc[i][j][r] = 0.f;

    const unsigned short* __restrict__ pB0 = wtT + (size_t)(2 * wave) * TILE_U + quad * 128 + l16 * 8;
    const unsigned short* __restrict__ pB1 = pB0 + TILE_U;
    const char* Ab = (const char*)Ash;
    const int swz = (l16 & 7) << 4;
    // even/odd ks bases: XOR touches bits 4-6 and ks*64 carries bit 6 -> two bases
    const int b0e = (l16 * 1280 + quad * 16) ^ swz;
    const int b0o = (l16 * 1280 + 64 + quad * 16) ^ swz;
    const int b1e = ((l16 + 16) * 1280 + quad * 16) ^ swz;
    const int b1o = ((l16 + 16) * 1280 + 64 + quad * 16) ^ swz;

    short8 xa0, xa1, xb0, xb1, ya0, ya1, yb0, yb1;
#define FLDA(P, s) \
    P##a0 = *(const short8*)(Ab + (((s) & 1) ? b0o : b0e) + ((s) >> 1) * 128); \
    P##a1 = *(const short8*)(Ab + (((s) & 1) ? b1o : b1e) + ((s) >> 1) * 128);
#define FLDB(P, s) \
    P##b0 = *(const short8*)(pB0 + (s) * 512); \
    P##b1 = *(const short8*)(pB1 + (s) * 512);
#define FLD(P, s) FLDA(P, s) FLDB(P, s)
#define FMM(P) \
    acc[0][0] = __builtin_amdgcn_mfma_f32_16x16x32_bf16(P##a0, P##b0, acc[0][0], 0, 0, 0); \
    acc[0][1] = __builtin_amdgcn_mfma_f32_16x16x32_bf16(P##a0, P##b1, acc[0][1], 0, 0, 0); \
    acc[1][0] = __builtin_amdgcn_mfma_f32_16x16x32_bf16(P##a1, P##b0, acc[1][0], 0, 0, 0); \
    acc[1][1] = __builtin_amdgcn_mfma_f32_16x16x32_bf16(P##a1, P##b1, acc[1][1], 0, 0, 0);

    // B loads are global (no LDS dependency): issue before the barrier
    FLDB(x, 0) FLDB(y, 1)
    __syncthreads();
    FLDA(x, 0) FLDA(y, 1)
    FMM(x) FLD(x, 2)
    FMM(y) FLD(y, 3)
    FMM(x) FLD(x, 4)
    FMM(y) FLD(y, 5)
    FMM(x) FLD(x, 6)
    FMM(y) FLD(y, 7)
    FMM(x) FLD(x, 8)
    FMM(y) FLD(y, 9)
    FMM(x) FLD(x, 10)
    FMM(y) FLD(y, 11)
    FMM(x) FLD(x, 12)
    FMM(y) FLD(y, 13)
    FMM(x) FLD(x, 14)
    FMM(y) FLD(y, 15)
    FMM(x) FLD(x, 16)
    FMM(y) FLD(y, 17)
    FMM(x) FLD(x, 18)
    FMM(y) FLD(y, 19)
    FMM(x)
    FMM(y)
#undef FLDA
#undef FLDB
#undef FLD
#undef FMM

    // ---- epilogue: o = (acc + bias)/deg, bf16 store, per-block BN partial stats
    // cntL valid across waves here: phase-3 __syncthreads() ordered phase-0 writes.
    float ssum[2] = {0.f, 0.f}, sssq[2] = {0.f, 0.f};
#pragma unroll
    for (int m = 0; m < 2; ++m) {
#pragma unroll
        for (int r = 0; r < 4; ++r) {
            const int lrow = m * 16 + quad * 4 + r;
            const int row = n0 + lrow;                 // always < N_ENTS (3125*32 exact)
            const float rdeg = 1.0f / fmaxf((float)cntL[lrow], 1.0f);
#pragma unroll
            for (int n = 0; n < 2; ++n) {
                const int col = (2 * wave + n) * 16 + l16;
                const float o = (acc[m][n][r] + bf2f(bsl[col])) * rdeg;
                out[(size_t)row * DIM + col] = f2bf(o);
                ssum[n] += o;
                sssq[n] += o * o;
            }
        }
    }
#pragma unroll
    for (int n = 0; n < 2; ++n) {
        float s = ssum[n], q2 = sssq[n];
        s += __shfl_xor(s, 16, 64);  s += __shfl_xor(s, 32, 64);
        q2 += __shfl_xor(q2, 16, 64); q2 += __shfl_xor(q2, 32, 64);
        if (quad == 0) {
            const int col = (2 * wave + n) * 16 + l16;
            pstats[(size_t)blockIdx.x * 256 + col] = s;
            pstats[(size_t)blockIdx.x * 256 + 128 + col] = q2;
        }
    }
}

// ---------------- reduce per-block stats -> st[256] ----------------
__global__ __launch_bounds__(256) void k_stats(const float* __restrict__ pstats,
                                               float* __restrict__ st) {
    const int o = threadIdx.x;
    const int b0 = blockIdx.x * 25;                // grid 125: 125*25 = 3125 exact
    float s = 0.f;
    for (int b = b0; b < b0 + 25; ++b)
        s += pstats[(size_t)b * 256 + o];
    atomicAdd(&st[o], s);
}

// ---------------- fused scoring: one BLOCK per sample (4 waves x 16 negs) ----------------
// head/rel gathered once per wave (8/sample vs 130), hr cached in registers; each wave
// issues its 16 neg-row gathers back-to-back (indices via coalesced negi load + shfl).
// 1024 blocks x 4 waves keeps wave parallelism high (r11's 256-block version did not).
__global__ __launch_bounds__(256) void k_score(
    const int* __restrict__ head, const int* __restrict__ rel,
    const int* __restrict__ tail, const int* __restrict__ negi,
    const unsigned short* __restrict__ emb, const unsigned short* __restrict__ rtab,
    const float* __restrict__ st1, const unsigned short* __restrict__ gm1,
    const unsigned short* __restrict__ bt1,
    void* __restrict__ outp, const int* __restrict__ flag)
{
    const int wave = threadIdx.x >> 6, lane = threadIdx.x & 63;
    const int i = blockIdx.x;              // grid exact: BATCH
    const float inv_n = 1.0f / (float)N_ENTS;
    const int f0 = lane * 2, f1 = f0 + 1;
    const float mu0 = st1[f0] * inv_n, mu1 = st1[f1] * inv_n;
    const float va0 = st1[DIM + f0] * inv_n - mu0 * mu0;
    const float va1 = st1[DIM + f1] * inv_n - mu1 * mu1;
    const float g0 = bf2f(gm1[f0]) * rsqrtf(va0 + BN_EPS);
    const float g1 = bf2f(gm1[f1]) * rsqrtf(va1 + BN_EPS);
    const float o0 = bf2f(bt1[f0]) - mu0 * g0;
    const float o1 = bf2f(bt1[f1]) - mu1 * g1;
    const int isbf = flag[0];

    const uint* __restrict__ x32 = (const uint*)emb;
    // neg indices: one coalesced load; lane l holds negi[i*64+l]
    const int nIdx = negi[i * 64 + lane];
    const uint hv = x32[(size_t)head[i] * 64 + lane];
    const uint rv = ((const uint*)rtab)[(size_t)rel[i] * 64 + lane];
    const float hr0 = fmaxf(fmaf(bflo(hv), g0, o0), 0.f) + bflo(rv);
    const float hr1 = fmaxf(fmaf(bfhi(hv), g1, o1), 0.f) + bfhi(rv);

    auto score1 = [&](uint tvv, int oidx) {
        const float t0 = fmaxf(fmaf(bflo(tvv), g0, o0), 0.f);
        const float t1 = fmaxf(fmaf(bfhi(tvv), g1, o1), 0.f);
        const float d0 = hr0 - t0, d1 = hr1 - t1;
        float s = d0 * d0 + d1 * d1;
#pragma unroll
        for (int m = 32; m >= 1; m >>= 1) s += __shfl_xor(s, m, 64);
        if (lane == 0) {
            const float v = -sqrtf(s);
            if (isbf) ((unsigned short*)outp)[oidx] = f2bf(v);
            else      ((float*)outp)[oidx] = v;
        }
    };

    // wave w scores 16 negs; all 16 gathers issued before first use
    uint a[16];
#pragma unroll
    for (int k = 0; k < 16; ++k)
        a[k] = x32[(size_t)__shfl(nIdx, wave * 16 + k, 64) * 64 + lane];
    if (wave == 0) score1(x32[(size_t)tail[i] * 64 + lane], i);   // pos score
#pragma unroll
    for (int k = 0; k < 16; ++k)
        score1(a[k], BATCH + i * 64 + wave * 16 + k);
}

extern "C" void kernel_launch(void* const* d_in, const int* in_sizes, int n_in,
                              void* d_out, int out_size, void* d_ws, size_t ws_size,
                              hipStream_t stream)
{
    const int* head = (const int*)d_in[0];
    const int* rel  = (const int*)d_in[1];
    const int* tail = (const int*)d_in[2];
    const int* negi = (const int*)d_in[3];
    const int* eidx = (const int*)d_in[4];
    const int* etyp = (const int*)d_in[5];
    const void* ent_tab = d_in[6];
    const void* rtab_in = d_in[7];
    const void* bases_in = d_in[8];
    const void* coeffs_in = d_in[9];
    const void* wsl_in = d_in[10];
    const void* bsl_in = d_in[11];
    const void* gamma_in = d_in[12];
    const void* beta_in = d_in[13];

    char* ws = (char*)d_ws;
    size_t off = 0;
    auto alloc = [&](size_t bytes) -> char* {
        char* p = ws + off;
        off += (bytes + 511) & ~(size_t)511;
        return p;
    };
    int* flag            = (int*)alloc(4);
    int* cnt             = (int*)alloc((size_t)N_ENTS * 4);
    uint* bucket         = (uint*)alloc((size_t)N_ENTS * BCAP * 4);             // 25.6 MB
    unsigned short* xrow = (unsigned short*)alloc((size_t)N_ENTS * DIM * 2);    // fp32-input path only
    unsigned short* outA = (unsigned short*)alloc((size_t)N_ENTS * DIM * 2);    // layer-0 raw out
    unsigned short* outB = (unsigned short*)alloc((size_t)N_ENTS * DIM * 2);    // layer-1 raw out
    unsigned short* par  = (unsigned short*)alloc((size_t)P_TOTAL * 2);
    unsigned short* WtT  = (unsigned short*)alloc((size_t)2 * 81920 * 2);
    float* cf32          = (float*)alloc((size_t)2 * 17 * 4 * 4);
    float* pstats        = (float*)alloc((size_t)NBLK2 * 256 * 4);              // 3.2 MB
    float* stats         = (float*)alloc(2 * 2 * DIM * 4);
    (void)ws_size; (void)in_sizes; (void)n_in; (void)out_size;

    const int* esrc = eidx;
    const int* edst = eidx + NEDGE;

    // 8 dispatches: detect(+stats zero), conv(+WtT+cf32+cnt zero+params),
    // fillB, fused0, stats0, fused1, stats1, score.
    k_detect<<<1, 256, 0, stream>>>((const unsigned int*)ent_tab, flag, stats);

    k_conv<<<B_GRID, 256, 0, stream>>>(
        ent_tab, xrow, rtab_in, bases_in, coeffs_in, wsl_in, bsl_in, gamma_in, beta_in,
        par, WtT, cf32, cnt, flag);

    k_fillB<<<NEDGE / 256, 256, 0, stream>>>(esrc, edst, etyp, cnt, bucket);

    // layer 0 (no BN on input)
    k_fused<<<NBLK2, 256, 0, stream>>>(
        bucket, cnt, cf32, xrow, ent_tab, flag, 0,
        stats, par + P_GAMMA, par + P_BETA,          // unused at lay 0
        WtT, par + P_BSL, outA, pstats);
    k_stats<<<125, 256, 0, stream>>>(pstats, stats);

    // layer 1 (BN0+ReLU fused on the fly)
    k_fused<<<NBLK2, 256, 0, stream>>>(
        bucket, cnt, cf32 + 68, outA, ent_tab, flag, 1,
        stats, par + P_GAMMA, par + P_BETA,
        WtT + 81920, par + P_BSL + DIM, outB, pstats);
    k_stats<<<125, 256, 0, stream>>>(pstats, stats + 2 * DIM);

    k_score<<<BATCH, 256, 0, stream>>>(
        head, rel, tail, negi, outB, par + P_REL,
        stats + 2 * DIM, par + P_GAMMA + DIM, par + P_BETA + DIM,
        d_out, flag);
}

// Round 13
// 334.712 us; speedup vs baseline: 1.1605x; 1.0087x over previous
//
#include <hip/hip_runtime.h>
#include <stdint.h>

// Problem constants
#define N_ENTS  100000
#define N_RELS  16
#define DIM     128
#define NB      4
#define TILE_U  10240           // ushorts per WtT n-tile: 80*16*8
#define NEDGE   640000
#define BATCH   1024
#define NNEG    64
#define BN_EPS  1e-5f
#define BCAP    64              // bucket capacity per node
#define SENTR   0x01000000u     // sentinel record: rel=16 (zero coeff), src=0
#define NPB     32              // nodes per fused block
#define NBLK2   3125            // N_ENTS/NPB exact

// merged k_conv block ranges
#define B_X     0               // [0,6250): x fp32->bf16 (early-exit if bf16)
#define B_CNT   6250            // [6250,6348): zero cnt (98 blocks of uint4)
#define B_TW    6348            // [6348,6428): WtT build from RAW inputs (80 blocks)
#define B_CF    6428            // cf32 table (1 block)
#define B_PAR   6429            // [6429,6440): small param convert (2816 elems)
#define B_GRID  6440

// converted-parameter buffer layout (ushort offsets) — only small params now
#define P_REL    0        // [16][128]
#define P_BSL    2048     // [2][128]
#define P_GAMMA  2304     // [2][128]
#define P_BETA   2560     // [2][128]
#define P_TOTAL  2816

typedef unsigned int uint;
typedef short short8 __attribute__((ext_vector_type(8)));
typedef float f4 __attribute__((ext_vector_type(4)));

__device__ __forceinline__ float bf2f(unsigned short u) {
    return __uint_as_float(((unsigned int)u) << 16);
}
__device__ __forceinline__ float bflo(unsigned int u) { return __uint_as_float(u << 16); }
__device__ __forceinline__ float bfhi(unsigned int u) { return __uint_as_float(u & 0xffff0000u); }
__device__ __forceinline__ unsigned short f2bf(float f) {
    unsigned int x = __float_as_uint(f);
    x += 0x7fffu + ((x >> 16) & 1u);
    return (unsigned short)(x >> 16);
}
__device__ __forceinline__ unsigned int pack2(float a, float b) {
    return (unsigned int)f2bf(a) | ((unsigned int)f2bf(b) << 16);
}

// ---------------- dtype detection (fp32 vs bf16 storage) + stats zero ----------------
__device__ __forceinline__ int bf16_like(unsigned int h) {
    unsigned int m = h & 0x7FFFu;
    return (m == 0u) || (m >= 0x2D00u && m < 0x4400u);
}
__global__ __launch_bounds__(256) void k_detect(const unsigned int* __restrict__ ent,
                                                int* __restrict__ flag,
                                                float* __restrict__ stats) {
    __shared__ int cnt[256];
    unsigned int u = ent[threadIdx.x];
    cnt[threadIdx.x] = bf16_like(u & 0xFFFFu) & bf16_like(u >> 16);
    stats[threadIdx.x] = 0.f;                      // zero stats[512] inline
    stats[256 + threadIdx.x] = 0.f;
    __syncthreads();
    for (int s = 128; s > 0; s >>= 1) {
        if (threadIdx.x < s) cnt[threadIdx.x] += cnt[threadIdx.x + s];
        __syncthreads();
    }
    if (threadIdx.x == 0) flag[0] = (cnt[0] >= 140) ? 1 : 0;
}

// ---------------- merged convert/setup kernel ----------------
// x convert (fp32 path), cnt zero, WtT build (from raw inputs), cf32, small params.
__device__ __forceinline__ unsigned short cvt1(const void* src, int i, int isbf) {
    return isbf ? ((const unsigned short*)src)[i] : f2bf(((const float*)src)[i]);
}
__global__ __launch_bounds__(256) void k_conv(
    const void* __restrict__ src, unsigned short* __restrict__ xrow,
    const void* __restrict__ rtab, const void* __restrict__ bases,
    const void* __restrict__ coeffs, const void* __restrict__ wsl,
    const void* __restrict__ bsl, const void* __restrict__ gamma,
    const void* __restrict__ beta,
    unsigned short* __restrict__ par, unsigned short* __restrict__ WtT,
    float* __restrict__ cf32, int* __restrict__ cnt, const int* __restrict__ flag)
{
    const int b = blockIdx.x;
    const int isbf = flag[0];
    if (b < B_CNT) {                               // ---- x conversion
        if (isbf) return;                          // bf16 input: ent used directly
        const int kc = threadIdx.x >> 4, r = threadIdx.x & 15;
        const int n = b * 16 + r;
        const size_t e0 = (size_t)n * DIM + kc * 8;
        const float4 f0 = *(const float4*)((const float*)src + e0);
        const float4 f1 = *(const float4*)((const float*)src + e0 + 4);
        uint4 w;
        w.x = pack2(f0.x, f0.y); w.y = pack2(f0.z, f0.w);
        w.z = pack2(f1.x, f1.y); w.w = pack2(f1.z, f1.w);
        *(uint4*)(xrow + e0) = w;
        return;
    }
    if (b < B_TW) {                                // ---- zero cnt via uint4 stores
        const int i = (b - B_CNT) * 256 + threadIdx.x;   // uint4 index
        if (i < N_ENTS / 4) {
            uint4 z = {0, 0, 0, 0};
            ((uint4*)cnt)[i] = z;
        }
        return;
    }
    if (b < B_CF) {                                // ---- WtT from RAW wsl/bases
        const int i = (b - B_TW) * 256 + threadIdx.x;    // [0, 20480)
        const int l = i / 10240;
        const int rem = i - l * 10240;
        const int jt2 = rem / 1280;
        const int rem2 = rem - jt2 * 1280;
        const int kc = rem2 >> 4, r = rem2 & 15;
        const int n = jt2 * 16 + r;
        unsigned short v[8];
#pragma unroll
        for (int e = 0; e < 8; ++e) {
            const int k = kc * 8 + e;
            v[e] = (k < DIM)
                ? cvt1(wsl,   l * DIM * DIM + k * DIM + n, isbf)
                : cvt1(bases, l * NB * DIM * DIM + (k - DIM) * DIM + n, isbf);
        }
        *(uint4*)(WtT + (size_t)l * 81920 + (size_t)jt2 * TILE_U + (size_t)kc * 128 + r * 8) = *(uint4*)v;
        return;
    }
    if (b == B_CF) {                               // ---- cf32 [2][17][4], rel=16 -> 0
        const int i = threadIdx.x;
        if (i < 2 * 17 * 4) {
            const int l = i / 68, rem = i - l * 68, r = rem >> 2, bb = rem & 3;
            const int idx = l * N_RELS * NB + r * NB + bb;
            cf32[i] = (r < N_RELS)
                ? (isbf ? bf2f(((const unsigned short*)coeffs)[idx])
                        : ((const float*)coeffs)[idx])
                : 0.f;
        }
        return;
    }
    // ---- small params: rel, bsl, gamma, beta
    const int i = (b - B_PAR) * 256 + threadIdx.x;
    if (i >= P_TOTAL) return;
    unsigned short v;
    if      (i < P_BSL)    v = cvt1(rtab,  i - P_REL,   isbf);
    else if (i < P_GAMMA)  v = cvt1(bsl,   i - P_BSL,   isbf);
    else if (i < P_BETA)   v = cvt1(gamma, i - P_GAMMA, isbf);
    else                   v = cvt1(beta,  i - P_BETA,  isbf);
    par[i] = v;
}

// ---------------- one-kernel bucket CSR: cnt + bucket[n][64] ----------------
__global__ __launch_bounds__(256) void k_fillB(const int* __restrict__ src, const int* __restrict__ dst,
                                               const int* __restrict__ et, int* __restrict__ cnt,
                                               uint* __restrict__ bucket) {
    const int e = blockIdx.x * 256 + threadIdx.x;   // grid exact: NEDGE/256
    const int d = dst[e];
    const int p = atomicAdd(&cnt[d], 1);
    if (p < BCAP) bucket[(size_t)d * BCAP + p] = (uint)src[e] | ((uint)et[e] << 20);
}

// ---------------- FUSED (BN of prev layer) + aggregate + GEMM + epilogue ----------------
// r10/r12-proven structure, LDS DIET (r13): records + cf stash live INSIDE Ash so
// LDS = 40960 exactly -> 4 blocks/CU (r10's 43520 dropped to 3 blocks, occ 35->27.5%).
// Lifetime disjointness (all within one wave's own 8 rows; swizzle XOR only permutes
// bits 4-6, so every write stays in its 256B region):
//  - records(16/node, 64B): row nd bytes 256..319 linear; overwritten only by that
//    node's b=0 aggregate store, which is AFTER its records are consumed.
//  - cf(272B/wave): row wave*8+7 bytes 512..783 (b=1/2 regions) — overwritten only at
//    the END of pr=3's consume, after the last cc read.
//  - cnt: wave-uniform s_loads (phase 2) + global reads (epilogue), no LDS.
// DO NOT TOUCH phase 2 shape: r7/r8/r11 register-pipelining variants all regressed.
__global__ __launch_bounds__(256, 4) void k_fused(
    const uint* __restrict__ bucket, const int* __restrict__ cnt,
    const float* __restrict__ cf, const unsigned short* __restrict__ xin,
    const void* __restrict__ ent, const int* __restrict__ flag, const int lay,
    const float* __restrict__ stp, const unsigned short* __restrict__ gprev,
    const unsigned short* __restrict__ bprev,
    const unsigned short* __restrict__ wtT, const unsigned short* __restrict__ bsl,
    unsigned short* __restrict__ out, float* __restrict__ pstats)
{
    __shared__ unsigned short Ash[NPB * 640];            // 40960 B exactly
    const int tid = threadIdx.x;
    const int wave = tid >> 6, lane = tid & 63;
    const int n0 = blockIdx.x * NPB;
    const float inv_n = 1.0f / (float)N_ENTS;

    const unsigned short* __restrict__ xs =
        (lay == 0 && flag[0]) ? (const unsigned short*)ent : xin;
    const int mybase = n0 + wave * 8;
    char* AshB = (char*)Ash;
    const int cfb = (wave * 8 + 7) * 1280 + 512;         // per-wave cf stash base

    // hoisted wave-uniform degree loads (s_load)
    int cns[8];
#pragma unroll
    for (int k = 0; k < 8; ++k) cns[k] = cnt[mybase + k];

    // ---- phase 0: stash bucket records (16/node) + cf table inside Ash (own rows)
    {
        const int nd = wave * 8 + (lane >> 3);           // this wave's nodes only
        const int p  = lane & 7;                         // record pair 0..7 (recs 0..15)
        const uint2 rv = *(const uint2*)(bucket + (size_t)(n0 + nd) * BCAP + p * 2);
        *(uint2*)(AshB + nd * 1280 + 256 + p * 8) = rv;
        if (lane < 17) {
            const float4 c4 = *(const float4*)(cf + lane * 4);
            *(float4*)(AshB + cfb + lane * 16) = c4;
        }
    }

    // per-lane BN coeffs for gather columns {2*lane, 2*lane+1} (identity for lay 0)
    float gnA = 1.f, ofA = 0.f, gnB = 1.f, ofB = 0.f;
    if (lay) {
        const int f0 = lane * 2, f1 = f0 + 1;
        const float mu0 = stp[f0] * inv_n, mu1 = stp[f1] * inv_n;
        const float va0 = stp[DIM + f0] * inv_n - mu0 * mu0;
        const float va1 = stp[DIM + f1] * inv_n - mu1 * mu1;
        gnA = bf2f(gprev[f0]) * rsqrtf(va0 + BN_EPS); ofA = bf2f(bprev[f0]) - mu0 * gnA;
        gnB = bf2f(gprev[f1]) * rsqrtf(va1 + BN_EPS); ofB = bf2f(bprev[f1]) - mu1 * gnB;
    }

    // ---- phase 1: stage self rows into LDS (k 0..127 = 256B/row), swizzled, BN-applied
    // rows r = tid>>3 = wave*8 + (lane>>3): per-wave row ownership, bytes 0..255 only.
    {
        const int r = tid >> 3, c = tid & 7;       // 32 rows; chunks c and c+8 (16B each)
        const size_t e0 = (size_t)(n0 + r) * DIM + c * 8;
        uint4 v0 = *(const uint4*)(xs + e0);
        uint4 v1 = *(const uint4*)(xs + e0 + 64);
        if (lay) {
            uint vv[8] = {v0.x, v0.y, v0.z, v0.w, v1.x, v1.y, v1.z, v1.w};
#pragma unroll
            for (int p = 0; p < 8; ++p) {
                const int f0 = c * 8 + (p >> 2) * 64 + (p & 3) * 2;
                const float mu0 = stp[f0] * inv_n, mu1 = stp[f0 + 1] * inv_n;
                const float va0 = stp[DIM + f0] * inv_n - mu0 * mu0;
                const float va1 = stp[DIM + f0 + 1] * inv_n - mu1 * mu1;
                const float g0 = bf2f(gprev[f0]) * rsqrtf(va0 + BN_EPS);
                const float g1 = bf2f(gprev[f0 + 1]) * rsqrtf(va1 + BN_EPS);
                const float o0 = bf2f(bprev[f0]) - mu0 * g0;
                const float o1 = bf2f(bprev[f0 + 1]) - mu1 * g1;
                const float w0 = fmaxf(fmaf(bflo(vv[p]), g0, o0), 0.f);
                const float w1 = fmaxf(fmaf(bfhi(vv[p]), g1, o1), 0.f);
                vv[p] = pack2(w0, w1);
            }
            v0.x = vv[0]; v0.y = vv[1]; v0.z = vv[2]; v0.w = vv[3];
            v1.x = vv[4]; v1.y = vv[5]; v1.z = vv[6]; v1.w = vv[7];
        }
        const int byte0 = (r * 1280 + c * 16) ^ ((r & 7) << 4);
        *(uint4*)(AshB + byte0) = v0;
        *(uint4*)(AshB + byte0 + 128) = v1;   // +128: bit7 only, outside XOR bits 4-6
    }

    // ---- phase 2: gather-aggregate; records from Ash stash, 2-node interleave
    const uint* __restrict__ x32 = (const uint*)xs;
    for (int pr = 0; pr < 4; ++pr) {
        const int la = wave * 8 + pr * 2;
        const int na = mybase + pr * 2;
        int ca = cns[pr * 2];     if (ca > BCAP) ca = BCAP;
        int cb = cns[pr * 2 + 1]; if (cb > BCAP) cb = BCAP;
        const int qm = ((ca > cb ? ca : cb) + 7) >> 3;
        float aLo[2][NB] = {{0.f,0.f,0.f,0.f},{0.f,0.f,0.f,0.f}};
        float aHi[2][NB] = {{0.f,0.f,0.f,0.f},{0.f,0.f,0.f,0.f}};
        const uint4* __restrict__ bkg = (const uint4*)(bucket + (size_t)na * BCAP);
        for (int j = 0; j < qm; ++j) {
            uint rec[2][8];
            uint xw[2][8];
            const int b8 = j * 8;
#pragma unroll
            for (int h = 0; h < 2; ++h) {
                const int cn = h ? cb : ca;
                if (b8 < cn) {
                    if (j < 2) {                         // records 0..15: Ash stash (broadcast)
#pragma unroll
                        for (int s = 0; s < 8; ++s)
                            rec[h][s] = *(const uint*)(AshB + (la + h) * 1280 + 256 + (b8 + s) * 4);
                    } else {                             // rare: records 16+ from global
                        const uint4 r0 = bkg[h * 16 + j * 2];
                        const uint4 r1 = bkg[h * 16 + j * 2 + 1];
                        rec[h][0] = r0.x; rec[h][1] = r0.y; rec[h][2] = r0.z; rec[h][3] = r0.w;
                        rec[h][4] = r1.x; rec[h][5] = r1.y; rec[h][6] = r1.z; rec[h][7] = r1.w;
                    }
#pragma unroll
                    for (int s = 0; s < 8; ++s) {
                        uint rr = rec[h][s];
                        if (b8 + s >= cn) rr = SENTR;    // tail mask: rel=16, src=0
                        rec[h][s] = rr;
                        xw[h][s] = x32[(size_t)(rr & 0xFFFFFu) * 64 + lane];
                    }
                }
            }
#pragma unroll
            for (int h = 0; h < 2; ++h) {
                const int cn = h ? cb : ca;
                if (b8 < cn) {
#pragma unroll
                    for (int s = 0; s < 8; ++s) {
                        const int rel = (int)(rec[h][s] >> 20);   // 16 -> zero coeffs
                        const float4 cc = *(const float4*)(AshB + cfb + rel * 16);  // broadcast
                        float xl, xh;
                        if (lay) {
                            xl = fmaxf(fmaf(bflo(xw[h][s]), gnA, ofA), 0.f);
                            xh = fmaxf(fmaf(bfhi(xw[h][s]), gnB, ofB), 0.f);
                        } else {
                            xl = bflo(xw[h][s]);
                            xh = bfhi(xw[h][s]);
                        }
                        aLo[h][0] = fmaf(cc.x, xl, aLo[h][0]);
                        aHi[h][0] = fmaf(cc.x, xh, aHi[h][0]);
                        aLo[h][1] = fmaf(cc.y, xl, aLo[h][1]);
                        aHi[h][1] = fmaf(cc.y, xh, aHi[h][1]);
                        aLo[h][2] = fmaf(cc.z, xl, aLo[h][2]);
                        aHi[h][2] = fmaf(cc.z, xh, aHi[h][2]);
                        aLo[h][3] = fmaf(cc.w, xl, aLo[h][3]);
                        aHi[h][3] = fmaf(cc.w, xh, aHi[h][3]);
                    }
                }
            }
        }
        // aggregate write AFTER this pr's records consumed (overwrites record stash;
        // pr=3's write overwrites the cf stash — nothing reads either afterwards)
#pragma unroll
        for (int h = 0; h < 2; ++h) {
            const int ra = wave * 8 + pr * 2 + h;
            const int swz = (ra & 7) << 4;
#pragma unroll
            for (int b = 0; b < NB; ++b) {
                // A[ra][128 + b*128 + 2*lane .. +1]  (bank-conflict-free: lane*4 stride)
                const int byte = (ra * 1280 + 256 + b * 256 + lane * 4) ^ swz;
                *(uint*)(AshB + byte) = pack2(aLo[h][b], aHi[h][b]);
            }
        }
    }

    // ---- phase 3: MFMA. wave w: m-tiles {0,1} x n-tiles {2w,2w+1}, K=640 (20 steps)
    const int quad = lane >> 4, l16 = lane & 15;
    f4 acc[2][2];
#pragma unroll
    for (int i = 0; i < 2; ++i)
#pragma unroll
        for (int j = 0; j < 2; ++j)
#pragma unroll
            for (int r = 0; r < 4; ++r) acc[i][j][r] = 0.f;

    const unsigned short* __restrict__ pB0 = wtT + (size_t)(2 * wave) * TILE_U + quad * 128 + l16 * 8;
    const unsigned short* __restrict__ pB1 = pB0 + TILE_U;
    const char* Ab = (const char*)Ash;
    const int swz = (l16 & 7) << 4;
    // even/odd ks bases: XOR touches bits 4-6 and ks*64 carries bit 6 -> two bases
    const int b0e = (l16 * 1280 + quad * 16) ^ swz;
    const int b0o = (l16 * 1280 + 64 + quad * 16) ^ swz;
    const int b1e = ((l16 + 16) * 1280 + quad * 16) ^ swz;
    const int b1o = ((l16 + 16) * 1280 + 64 + quad * 16) ^ swz;

    short8 xa0, xa1, xb0, xb1, ya0, ya1, yb0, yb1;
#define FLDA(P, s) \
    P##a0 = *(const short8*)(Ab + (((s) & 1) ? b0o : b0e) + ((s) >> 1) * 128); \
    P##a1 = *(const short8*)(Ab + (((s) & 1) ? b1o : b1e) + ((s) >> 1) * 128);
#define FLDB(P, s) \
    P##b0 = *(const short8*)(pB0 + (s) * 512); \
    P##b1 = *(const short8*)(pB1 + (s) * 512);
#define FLD(P, s) FLDA(P, s) FLDB(P, s)
#define FMM(P) \
    acc[0][0] = __builtin_amdgcn_mfma_f32_16x16x32_bf16(P##a0, P##b0, acc[0][0], 0, 0, 0); \
    acc[0][1] = __builtin_amdgcn_mfma_f32_16x16x32_bf16(P##a0, P##b1, acc[0][1], 0, 0, 0); \
    acc[1][0] = __builtin_amdgcn_mfma_f32_16x16x32_bf16(P##a1, P##b0, acc[1][0], 0, 0, 0); \
    acc[1][1] = __builtin_amdgcn_mfma_f32_16x16x32_bf16(P##a1, P##b1, acc[1][1], 0, 0, 0);

    // B loads are global (no LDS dependency): issue before the barrier
    FLDB(x, 0) FLDB(y, 1)
    __syncthreads();
    FLDA(x, 0) FLDA(y, 1)
    FMM(x) FLD(x, 2)
    FMM(y) FLD(y, 3)
    FMM(x) FLD(x, 4)
    FMM(y) FLD(y, 5)
    FMM(x) FLD(x, 6)
    FMM(y) FLD(y, 7)
    FMM(x) FLD(x, 8)
    FMM(y) FLD(y, 9)
    FMM(x) FLD(x, 10)
    FMM(y) FLD(y, 11)
    FMM(x) FLD(x, 12)
    FMM(y) FLD(y, 13)
    FMM(x) FLD(x, 14)
    FMM(y) FLD(y, 15)
    FMM(x) FLD(x, 16)
    FMM(y) FLD(y, 17)
    FMM(x) FLD(x, 18)
    FMM(y) FLD(y, 19)
    FMM(x)
    FMM(y)
#undef FLDA
#undef FLDB
#undef FLD
#undef FMM

    // ---- epilogue: o = (acc + bias)/deg, bf16 store, per-block BN partial stats
    float ssum[2] = {0.f, 0.f}, sssq[2] = {0.f, 0.f};
#pragma unroll
    for (int m = 0; m < 2; ++m) {
#pragma unroll
        for (int r = 0; r < 4; ++r) {
            const int row = n0 + m * 16 + quad * 4 + r;    // always < N_ENTS (3125*32 exact)
            const float rdeg = 1.0f / fmaxf((float)cnt[row], 1.0f);
#pragma unroll
            for (int n = 0; n < 2; ++n) {
                const int col = (2 * wave + n) * 16 + l16;
                const float o = (acc[m][n][r] + bf2f(bsl[col])) * rdeg;
                out[(size_t)row * DIM + col] = f2bf(o);
                ssum[n] += o;
                sssq[n] += o * o;
            }
        }
    }
#pragma unroll
    for (int n = 0; n < 2; ++n) {
        float s = ssum[n], q2 = sssq[n];
        s += __shfl_xor(s, 16, 64);  s += __shfl_xor(s, 32, 64);
        q2 += __shfl_xor(q2, 16, 64); q2 += __shfl_xor(q2, 32, 64);
        if (quad == 0) {
            const int col = (2 * wave + n) * 16 + l16;
            pstats[(size_t)blockIdx.x * 256 + col] = s;
            pstats[(size_t)blockIdx.x * 256 + 128 + col] = q2;
        }
    }
}

// ---------------- reduce per-block stats -> st[256] ----------------
__global__ __launch_bounds__(256) void k_stats(const float* __restrict__ pstats,
                                               float* __restrict__ st) {
    const int o = threadIdx.x;
    const int b0 = blockIdx.x * 25;                // grid 125: 125*25 = 3125 exact
    float s = 0.f;
    for (int b = b0; b < b0 + 25; ++b)
        s += pstats[(size_t)b * 256 + o];
    atomicAdd(&st[o], s);
}

// ---------------- fused scoring: one BLOCK per sample (4 waves x 16 negs) ----------------
// r12-proven: head/rel gathered once per wave, hr cached; 16 neg gathers issued
// back-to-back per wave (indices via coalesced negi load + shfl). 1024 blocks.
__global__ __launch_bounds__(256) void k_score(
    const int* __restrict__ head, const int* __restrict__ rel,
    const int* __restrict__ tail, const int* __restrict__ negi,
    const unsigned short* __restrict__ emb, const unsigned short* __restrict__ rtab,
    const float* __restrict__ st1, const unsigned short* __restrict__ gm1,
    const unsigned short* __restrict__ bt1,
    void* __restrict__ outp, const int* __restrict__ flag)
{
    const int wave = threadIdx.x >> 6, lane = threadIdx.x & 63;
    const int i = blockIdx.x;              // grid exact: BATCH
    const float inv_n = 1.0f / (float)N_ENTS;
    const int f0 = lane * 2, f1 = f0 + 1;
    const float mu0 = st1[f0] * inv_n, mu1 = st1[f1] * inv_n;
    const float va0 = st1[DIM + f0] * inv_n - mu0 * mu0;
    const float va1 = st1[DIM + f1] * inv_n - mu1 * mu1;
    const float g0 = bf2f(gm1[f0]) * rsqrtf(va0 + BN_EPS);
    const float g1 = bf2f(gm1[f1]) * rsqrtf(va1 + BN_EPS);
    const float o0 = bf2f(bt1[f0]) - mu0 * g0;
    const float o1 = bf2f(bt1[f1]) - mu1 * g1;
    const int isbf = flag[0];

    const uint* __restrict__ x32 = (const uint*)emb;
    // neg indices: one coalesced load; lane l holds negi[i*64+l]
    const int nIdx = negi[i * 64 + lane];
    const uint hv = x32[(size_t)head[i] * 64 + lane];
    const uint rv = ((const uint*)rtab)[(size_t)rel[i] * 64 + lane];
    const float hr0 = fmaxf(fmaf(bflo(hv), g0, o0), 0.f) + bflo(rv);
    const float hr1 = fmaxf(fmaf(bfhi(hv), g1, o1), 0.f) + bfhi(rv);

    auto score1 = [&](uint tvv, int oidx) {
        const float t0 = fmaxf(fmaf(bflo(tvv), g0, o0), 0.f);
        const float t1 = fmaxf(fmaf(bfhi(tvv), g1, o1), 0.f);
        const float d0 = hr0 - t0, d1 = hr1 - t1;
        float s = d0 * d0 + d1 * d1;
#pragma unroll
        for (int m = 32; m >= 1; m >>= 1) s += __shfl_xor(s, m, 64);
        if (lane == 0) {
            const float v = -sqrtf(s);
            if (isbf) ((unsigned short*)outp)[oidx] = f2bf(v);
            else      ((float*)outp)[oidx] = v;
        }
    };

    // wave w scores 16 negs; all 16 gathers issued before first use
    uint a[16];
#pragma unroll
    for (int k = 0; k < 16; ++k)
        a[k] = x32[(size_t)__shfl(nIdx, wave * 16 + k, 64) * 64 + lane];
    if (wave == 0) score1(x32[(size_t)tail[i] * 64 + lane], i);   // pos score
#pragma unroll
    for (int k = 0; k < 16; ++k)
        score1(a[k], BATCH + i * 64 + wave * 16 + k);
}

extern "C" void kernel_launch(void* const* d_in, const int* in_sizes, int n_in,
                              void* d_out, int out_size, void* d_ws, size_t ws_size,
                              hipStream_t stream)
{
    const int* head = (const int*)d_in[0];
    const int* rel  = (const int*)d_in[1];
    const int* tail = (const int*)d_in[2];
    const int* negi = (const int*)d_in[3];
    const int* eidx = (const int*)d_in[4];
    const int* etyp = (const int*)d_in[5];
    const void* ent_tab = d_in[6];
    const void* rtab_in = d_in[7];
    const void* bases_in = d_in[8];
    const void* coeffs_in = d_in[9];
    const void* wsl_in = d_in[10];
    const void* bsl_in = d_in[11];
    const void* gamma_in = d_in[12];
    const void* beta_in = d_in[13];

    char* ws = (char*)d_ws;
    size_t off = 0;
    auto alloc = [&](size_t bytes) -> char* {
        char* p = ws + off;
        off += (bytes + 511) & ~(size_t)511;
        return p;
    };
    int* flag            = (int*)alloc(4);
    int* cnt             = (int*)alloc((size_t)N_ENTS * 4);
    uint* bucket         = (uint*)alloc((size_t)N_ENTS * BCAP * 4);             // 25.6 MB
    unsigned short* xrow = (unsigned short*)alloc((size_t)N_ENTS * DIM * 2);    // fp32-input path only
    unsigned short* outA = (unsigned short*)alloc((size_t)N_ENTS * DIM * 2);    // layer-0 raw out
    unsigned short* outB = (unsigned short*)alloc((size_t)N_ENTS * DIM * 2);    // layer-1 raw out
    unsigned short* par  = (unsigned short*)alloc((size_t)P_TOTAL * 2);
    unsigned short* WtT  = (unsigned short*)alloc((size_t)2 * 81920 * 2);
    float* cf32          = (float*)alloc((size_t)2 * 17 * 4 * 4);
    float* pstats        = (float*)alloc((size_t)NBLK2 * 256 * 4);              // 3.2 MB
    float* stats         = (float*)alloc(2 * 2 * DIM * 4);
    (void)ws_size; (void)in_sizes; (void)n_in; (void)out_size;

    const int* esrc = eidx;
    const int* edst = eidx + NEDGE;

    // 8 dispatches: detect(+stats zero), conv(+WtT+cf32+cnt zero+params),
    // fillB, fused0, stats0, fused1, stats1, score.
    k_detect<<<1, 256, 0, stream>>>((const unsigned int*)ent_tab, flag, stats);

    k_conv<<<B_GRID, 256, 0, stream>>>(
        ent_tab, xrow, rtab_in, bases_in, coeffs_in, wsl_in, bsl_in, gamma_in, beta_in,
        par, WtT, cf32, cnt, flag);

    k_fillB<<<NEDGE / 256, 256, 0, stream>>>(esrc, edst, etyp, cnt, bucket);

    // layer 0 (no BN on input)
    k_fused<<<NBLK2, 256, 0, stream>>>(
        bucket, cnt, cf32, xrow, ent_tab, flag, 0,
        stats, par + P_GAMMA, par + P_BETA,          // unused at lay 0
        WtT, par + P_BSL, outA, pstats);
    k_stats<<<125, 256, 0, stream>>>(pstats, stats);

    // layer 1 (BN0+ReLU fused on the fly)
    k_fused<<<NBLK2, 256, 0, stream>>>(
        bucket, cnt, cf32 + 68, outA, ent_tab, flag, 1,
        stats, par + P_GAMMA, par + P_BETA,
        WtT + 81920, par + P_BSL + DIM, outB, pstats);
    k_stats<<<125, 256, 0, stream>>>(pstats, stats + 2 * DIM);

    k_score<<<BATCH, 256, 0, stream>>>(
        head, rel, tail, negi, outB, par + P_REL,
        stats + 2 * DIM, par + P_GAMMA + DIM, par + P_BETA + DIM,
        d_out, flag);
}

// Round 15
// 305.382 us; speedup vs baseline: 1.2720x; 1.0960x over previous
//
#include <hip/hip_runtime.h>
#include <stdint.h>

// Problem constants
#define N_ENTS  100000
#define N_RELS  16
#define DIM     128
#define NB      4
#define TILE_U  10240           // ushorts per WtT n-tile: 80*16*8
#define NEDGE   640000
#define BATCH   1024
#define NNEG    64
#define BN_EPS  1e-5f
#define BCAP    64              // bucket capacity per node
#define SENTR   0x01000000u     // sentinel record: rel=16 (zero coeff), src=0
#define NPB     32              // nodes per fused block
#define NBLK2   3125            // N_ENTS/NPB exact

// merged k_conv block ranges
#define B_X     0               // [0,6250): x fp32->bf16 (early-exit if bf16)
#define B_CNT   6250            // [6250,6348): zero cnt (98 blocks of uint4)
#define B_TW    6348            // [6348,6428): WtT build from RAW inputs (80 blocks)
#define B_CF    6428            // cf32 table (1 block)
#define B_PAR   6429            // [6429,6440): small param convert (2816 elems)
#define B_GRID  6440

// converted-parameter buffer layout (ushort offsets) — only small params now
#define P_REL    0        // [16][128]
#define P_BSL    2048     // [2][128]
#define P_GAMMA  2304     // [2][128]
#define P_BETA   2560     // [2][128]
#define P_TOTAL  2816

typedef unsigned int uint;
typedef short short8 __attribute__((ext_vector_type(8)));
typedef float f4 __attribute__((ext_vector_type(4)));

__device__ __forceinline__ float bf2f(unsigned short u) {
    return __uint_as_float(((unsigned int)u) << 16);
}
__device__ __forceinline__ float bflo(unsigned int u) { return __uint_as_float(u << 16); }
__device__ __forceinline__ float bfhi(unsigned int u) { return __uint_as_float(u & 0xffff0000u); }
__device__ __forceinline__ unsigned short f2bf(float f) {
    unsigned int x = __float_as_uint(f);
    x += 0x7fffu + ((x >> 16) & 1u);
    return (unsigned short)(x >> 16);
}
__device__ __forceinline__ unsigned int pack2(float a, float b) {
    return (unsigned int)f2bf(a) | ((unsigned int)f2bf(b) << 16);
}

// ---------------- dtype detection (fp32 vs bf16 storage) + stats zero ----------------
__device__ __forceinline__ int bf16_like(unsigned int h) {
    unsigned int m = h & 0x7FFFu;
    return (m == 0u) || (m >= 0x2D00u && m < 0x4400u);
}
__global__ __launch_bounds__(256) void k_detect(const unsigned int* __restrict__ ent,
                                                int* __restrict__ flag,
                                                float* __restrict__ stats) {
    __shared__ int cnt[256];
    unsigned int u = ent[threadIdx.x];
    cnt[threadIdx.x] = bf16_like(u & 0xFFFFu) & bf16_like(u >> 16);
    stats[threadIdx.x] = 0.f;                      // zero stats[512] inline
    stats[256 + threadIdx.x] = 0.f;
    __syncthreads();
    for (int s = 128; s > 0; s >>= 1) {
        if (threadIdx.x < s) cnt[threadIdx.x] += cnt[threadIdx.x + s];
        __syncthreads();
    }
    if (threadIdx.x == 0) flag[0] = (cnt[0] >= 140) ? 1 : 0;
}

// ---------------- merged convert/setup kernel ----------------
// x convert (fp32 path), cnt zero, WtT build (from raw inputs), cf32, small params.
__device__ __forceinline__ unsigned short cvt1(const void* src, int i, int isbf) {
    return isbf ? ((const unsigned short*)src)[i] : f2bf(((const float*)src)[i]);
}
__global__ __launch_bounds__(256) void k_conv(
    const void* __restrict__ src, unsigned short* __restrict__ xrow,
    const void* __restrict__ rtab, const void* __restrict__ bases,
    const void* __restrict__ coeffs, const void* __restrict__ wsl,
    const void* __restrict__ bsl, const void* __restrict__ gamma,
    const void* __restrict__ beta,
    unsigned short* __restrict__ par, unsigned short* __restrict__ WtT,
    float* __restrict__ cf32, int* __restrict__ cnt, const int* __restrict__ flag)
{
    const int b = blockIdx.x;
    const int isbf = flag[0];
    if (b < B_CNT) {                               // ---- x conversion
        if (isbf) return;                          // bf16 input: ent used directly
        const int kc = threadIdx.x >> 4, r = threadIdx.x & 15;
        const int n = b * 16 + r;
        const size_t e0 = (size_t)n * DIM + kc * 8;
        const float4 f0 = *(const float4*)((const float*)src + e0);
        const float4 f1 = *(const float4*)((const float*)src + e0 + 4);
        uint4 w;
        w.x = pack2(f0.x, f0.y); w.y = pack2(f0.z, f0.w);
        w.z = pack2(f1.x, f1.y); w.w = pack2(f1.z, f1.w);
        *(uint4*)(xrow + e0) = w;
        return;
    }
    if (b < B_TW) {                                // ---- zero cnt via uint4 stores
        const int i = (b - B_CNT) * 256 + threadIdx.x;   // uint4 index
        if (i < N_ENTS / 4) {
            uint4 z = {0, 0, 0, 0};
            ((uint4*)cnt)[i] = z;
        }
        return;
    }
    if (b < B_CF) {                                // ---- WtT from RAW wsl/bases
        const int i = (b - B_TW) * 256 + threadIdx.x;    // [0, 20480)
        const int l = i / 10240;
        const int rem = i - l * 10240;
        const int jt2 = rem / 1280;
        const int rem2 = rem - jt2 * 1280;
        const int kc = rem2 >> 4, r = rem2 & 15;
        const int n = jt2 * 16 + r;
        unsigned short v[8];
#pragma unroll
        for (int e = 0; e < 8; ++e) {
            const int k = kc * 8 + e;
            v[e] = (k < DIM)
                ? cvt1(wsl,   l * DIM * DIM + k * DIM + n, isbf)
                : cvt1(bases, l * NB * DIM * DIM + (k - DIM) * DIM + n, isbf);
        }
        *(uint4*)(WtT + (size_t)l * 81920 + (size_t)jt2 * TILE_U + (size_t)kc * 128 + r * 8) = *(uint4*)v;
        return;
    }
    if (b == B_CF) {                               // ---- cf32 [2][17][4], rel=16 -> 0
        const int i = threadIdx.x;
        if (i < 2 * 17 * 4) {
            const int l = i / 68, rem = i - l * 68, r = rem >> 2, bb = rem & 3;
            const int idx = l * N_RELS * NB + r * NB + bb;
            cf32[i] = (r < N_RELS)
                ? (isbf ? bf2f(((const unsigned short*)coeffs)[idx])
                        : ((const float*)coeffs)[idx])
                : 0.f;
        }
        return;
    }
    // ---- small params: rel, bsl, gamma, beta
    const int i = (b - B_PAR) * 256 + threadIdx.x;
    if (i >= P_TOTAL) return;
    unsigned short v;
    if      (i < P_BSL)    v = cvt1(rtab,  i - P_REL,   isbf);
    else if (i < P_GAMMA)  v = cvt1(bsl,   i - P_BSL,   isbf);
    else if (i < P_BETA)   v = cvt1(gamma, i - P_GAMMA, isbf);
    else                   v = cvt1(beta,  i - P_BETA,  isbf);
    par[i] = v;
}

// ---------------- one-kernel bucket CSR: cnt + bucket[n][64] ----------------
__global__ __launch_bounds__(256) void k_fillB(const int* __restrict__ src, const int* __restrict__ dst,
                                               const int* __restrict__ et, int* __restrict__ cnt,
                                               uint* __restrict__ bucket) {
    const int e = blockIdx.x * 256 + threadIdx.x;   // grid exact: NEDGE/256
    const int d = dst[e];
    const int p = atomicAdd(&cnt[d], 1);
    if (p < BCAP) bucket[(size_t)d * BCAP + p] = (uint)src[e] | ((uint)et[e] << 20);
}

// ---------------- FUSED (BN of prev layer) + aggregate + GEMM + epilogue ----------------
// r13-proven structure (LDS 40960 exact, records+cf stashed inside Ash). r14:
// template<LAY> (layer-0 loop drops BN ops, compile-time) + straight-line first-8
// (unconditional sentinel-masked block for both nodes, rare tail for deg>8).
// VGPR is free up to 128 here (LDS caps residency at 4 blocks = 4 waves/SIMD).
// DO NOT: register ping-pong pipelining (r7/r11), atomic stats (r8). Measured.
template<int LAY>
__global__ __launch_bounds__(256, 4) void k_fused(
    const uint* __restrict__ bucket, const int* __restrict__ cnt,
    const float* __restrict__ cf, const unsigned short* __restrict__ xin,
    const void* __restrict__ ent, const int* __restrict__ flag,
    const float* __restrict__ stp, const unsigned short* __restrict__ gprev,
    const unsigned short* __restrict__ bprev,
    const unsigned short* __restrict__ wtT, const unsigned short* __restrict__ bsl,
    unsigned short* __restrict__ out, float* __restrict__ pstats)
{
    __shared__ unsigned short Ash[NPB * 640];            // 40960 B exactly
    const int tid = threadIdx.x;
    const int wave = tid >> 6, lane = tid & 63;
    const int n0 = blockIdx.x * NPB;
    const float inv_n = 1.0f / (float)N_ENTS;

    const unsigned short* __restrict__ xs =
        (LAY == 0 && flag[0]) ? (const unsigned short*)ent : xin;
    const int mybase = n0 + wave * 8;
    char* AshB = (char*)Ash;
    const int cfb = (wave * 8 + 7) * 1280 + 512;         // per-wave cf stash base

    // hoisted wave-uniform degree loads (s_load)
    int cns[8];
#pragma unroll
    for (int k = 0; k < 8; ++k) cns[k] = cnt[mybase + k];

    // ---- phase 0: stash bucket records (16/node) + cf table inside Ash (own rows)
    {
        const int nd = wave * 8 + (lane >> 3);           // this wave's nodes only
        const int p  = lane & 7;                         // record pair 0..7 (recs 0..15)
        const uint2 rv = *(const uint2*)(bucket + (size_t)(n0 + nd) * BCAP + p * 2);
        *(uint2*)(AshB + nd * 1280 + 256 + p * 8) = rv;
        if (lane < 17) {
            const float4 c4 = *(const float4*)(cf + lane * 4);
            *(float4*)(AshB + cfb + lane * 16) = c4;
        }
    }

    // per-lane BN coeffs for gather columns {2*lane, 2*lane+1} (layer 1 only)
    float gnA = 1.f, ofA = 0.f, gnB = 1.f, ofB = 0.f;
    if (LAY) {
        const int f0 = lane * 2, f1 = f0 + 1;
        const float mu0 = stp[f0] * inv_n, mu1 = stp[f1] * inv_n;
        const float va0 = stp[DIM + f0] * inv_n - mu0 * mu0;
        const float va1 = stp[DIM + f1] * inv_n - mu1 * mu1;
        gnA = bf2f(gprev[f0]) * rsqrtf(va0 + BN_EPS); ofA = bf2f(bprev[f0]) - mu0 * gnA;
        gnB = bf2f(gprev[f1]) * rsqrtf(va1 + BN_EPS); ofB = bf2f(bprev[f1]) - mu1 * gnB;
    }

    // ---- phase 1: stage self rows into LDS (k 0..127 = 256B/row), swizzled, BN-applied
    {
        const int r = tid >> 3, c = tid & 7;       // 32 rows; chunks c and c+8 (16B each)
        const size_t e0 = (size_t)(n0 + r) * DIM + c * 8;
        uint4 v0 = *(const uint4*)(xs + e0);
        uint4 v1 = *(const uint4*)(xs + e0 + 64);
        if (LAY) {
            uint vv[8] = {v0.x, v0.y, v0.z, v0.w, v1.x, v1.y, v1.z, v1.w};
#pragma unroll
            for (int p = 0; p < 8; ++p) {
                const int f0 = c * 8 + (p >> 2) * 64 + (p & 3) * 2;
                const float mu0 = stp[f0] * inv_n, mu1 = stp[f0 + 1] * inv_n;
                const float va0 = stp[DIM + f0] * inv_n - mu0 * mu0;
                const float va1 = stp[DIM + f0 + 1] * inv_n - mu1 * mu1;
                const float g0 = bf2f(gprev[f0]) * rsqrtf(va0 + BN_EPS);
                const float g1 = bf2f(gprev[f0 + 1]) * rsqrtf(va1 + BN_EPS);
                const float o0 = bf2f(bprev[f0]) - mu0 * g0;
                const float o1 = bf2f(bprev[f0 + 1]) - mu1 * g1;
                const float w0 = fmaxf(fmaf(bflo(vv[p]), g0, o0), 0.f);
                const float w1 = fmaxf(fmaf(bfhi(vv[p]), g1, o1), 0.f);
                vv[p] = pack2(w0, w1);
            }
            v0.x = vv[0]; v0.y = vv[1]; v0.z = vv[2]; v0.w = vv[3];
            v1.x = vv[4]; v1.y = vv[5]; v1.z = vv[6]; v1.w = vv[7];
        }
        const int byte0 = (r * 1280 + c * 16) ^ ((r & 7) << 4);
        *(uint4*)(AshB + byte0) = v0;
        *(uint4*)(AshB + byte0 + 128) = v1;   // +128: bit7 only, outside XOR bits 4-6
    }

    // ---- phase 2: gather-aggregate; straight-line first-8 (sentinel-masked), rare tail
    const uint* __restrict__ x32 = (const uint*)xs;
    for (int pr = 0; pr < 4; ++pr) {
        const int la = wave * 8 + pr * 2;
        const int na = mybase + pr * 2;
        int ca = cns[pr * 2];     if (ca > BCAP) ca = BCAP;
        int cb = cns[pr * 2 + 1]; if (cb > BCAP) cb = BCAP;
        float aLo[2][NB] = {{0.f,0.f,0.f,0.f},{0.f,0.f,0.f,0.f}};
        float aHi[2][NB] = {{0.f,0.f,0.f,0.f},{0.f,0.f,0.f,0.f}};

        // first 8 records of BOTH nodes: unconditional (cn<=8 handled by sentinels;
        // deg-0 nodes gather row 0 wastefully but add zero — 0.2% of nodes)
        uint rec[2][8], xw[2][8];
#pragma unroll
        for (int h = 0; h < 2; ++h) {
            const int cn = h ? cb : ca;
#pragma unroll
            for (int s = 0; s < 8; ++s) {
                uint rr = *(const uint*)(AshB + (la + h) * 1280 + 256 + s * 4);
                if (s >= cn) rr = SENTR;             // tail mask: rel=16, src=0
                rec[h][s] = rr;
                xw[h][s] = x32[(size_t)(rr & 0xFFFFFu) * 64 + lane];
            }
        }
#pragma unroll
        for (int h = 0; h < 2; ++h) {
#pragma unroll
            for (int s = 0; s < 8; ++s) {
                const int rel = (int)(rec[h][s] >> 20);   // 16 -> zero coeffs
                const float4 cc = *(const float4*)(AshB + cfb + rel * 16);  // broadcast
                float xl, xh;
                if (LAY) {
                    xl = fmaxf(fmaf(bflo(xw[h][s]), gnA, ofA), 0.f);
                    xh = fmaxf(fmaf(bfhi(xw[h][s]), gnB, ofB), 0.f);
                } else {
                    xl = bflo(xw[h][s]);
                    xh = bfhi(xw[h][s]);
                }
                aLo[h][0] = fmaf(cc.x, xl, aLo[h][0]);
                aHi[h][0] = fmaf(cc.x, xh, aHi[h][0]);
                aLo[h][1] = fmaf(cc.y, xl, aLo[h][1]);
                aHi[h][1] = fmaf(cc.y, xh, aHi[h][1]);
                aLo[h][2] = fmaf(cc.z, xl, aLo[h][2]);
                aHi[h][2] = fmaf(cc.z, xh, aHi[h][2]);
                aLo[h][3] = fmaf(cc.w, xl, aLo[h][3]);
                aHi[h][3] = fmaf(cc.w, xh, aHi[h][3]);
            }
        }
        // tail (deg>8, P~19%): j=1 records from Ash stash, j>=2 from global
#pragma unroll
        for (int h = 0; h < 2; ++h) {
            const int cn = h ? cb : ca;
            const uint4* __restrict__ bkg = (const uint4*)(bucket + (size_t)(na + h) * BCAP);
            for (int j = 1; j * 8 < cn; ++j) {
                const int b8 = j * 8;
                uint trec[8], txw[8];
                if (j < 2) {
#pragma unroll
                    for (int s = 0; s < 8; ++s)
                        trec[s] = *(const uint*)(AshB + (la + h) * 1280 + 256 + (b8 + s) * 4);
                } else {
                    const uint4 r0 = bkg[j * 2];
                    const uint4 r1 = bkg[j * 2 + 1];
                    trec[0] = r0.x; trec[1] = r0.y; trec[2] = r0.z; trec[3] = r0.w;
                    trec[4] = r1.x; trec[5] = r1.y; trec[6] = r1.z; trec[7] = r1.w;
                }
#pragma unroll
                for (int s = 0; s < 8; ++s) {
                    uint rr = trec[s];
                    if (b8 + s >= cn) rr = SENTR;
                    trec[s] = rr;
                    txw[s] = x32[(size_t)(rr & 0xFFFFFu) * 64 + lane];
                }
#pragma unroll
                for (int s = 0; s < 8; ++s) {
                    const int rel = (int)(trec[s] >> 20);
                    const float4 cc = *(const float4*)(AshB + cfb + rel * 16);
                    float xl, xh;
                    if (LAY) {
                        xl = fmaxf(fmaf(bflo(txw[s]), gnA, ofA), 0.f);
                        xh = fmaxf(fmaf(bfhi(txw[s]), gnB, ofB), 0.f);
                    } else {
                        xl = bflo(txw[s]);
                        xh = bfhi(txw[s]);
                    }
                    aLo[h][0] = fmaf(cc.x, xl, aLo[h][0]);
                    aHi[h][0] = fmaf(cc.x, xh, aHi[h][0]);
                    aLo[h][1] = fmaf(cc.y, xl, aLo[h][1]);
                    aHi[h][1] = fmaf(cc.y, xh, aHi[h][1]);
                    aLo[h][2] = fmaf(cc.z, xl, aLo[h][2]);
                    aHi[h][2] = fmaf(cc.z, xh, aHi[h][2]);
                    aLo[h][3] = fmaf(cc.w, xl, aLo[h][3]);
                    aHi[h][3] = fmaf(cc.w, xh, aHi[h][3]);
                }
            }
        }
        // aggregate write AFTER this pr's records consumed (overwrites record stash;
        // pr=3's write overwrites the cf stash — nothing reads either afterwards)
#pragma unroll
        for (int h = 0; h < 2; ++h) {
            const int ra = wave * 8 + pr * 2 + h;
            const int swz = (ra & 7) << 4;
#pragma unroll
            for (int b = 0; b < NB; ++b) {
                // A[ra][128 + b*128 + 2*lane .. +1]  (bank-conflict-free: lane*4 stride)
                const int byte = (ra * 1280 + 256 + b * 256 + lane * 4) ^ swz;
                *(uint*)(AshB + byte) = pack2(aLo[h][b], aHi[h][b]);
            }
        }
    }

    // ---- phase 3: MFMA. wave w: m-tiles {0,1} x n-tiles {2w,2w+1}, K=640 (20 steps)
    const int quad = lane >> 4, l16 = lane & 15;
    f4 acc[2][2];
#pragma unroll
    for (int i = 0; i < 2; ++i)
#pragma unroll
        for (int j = 0; j < 2; ++j)
#pragma unroll
            for (int r = 0; r < 4; ++r) acc[i][j][r] = 0.f;

    const unsigned short* __restrict__ pB0 = wtT + (size_t)(2 * wave) * TILE_U + quad * 128 + l16 * 8;
    const unsigned short* __restrict__ pB1 = pB0 + TILE_U;
    const char* Ab = (const char*)Ash;
    const int swz = (l16 & 7) << 4;
    // even/odd ks bases: XOR touches bits 4-6 and ks*64 carries bit 6 -> two bases
    const int b0e = (l16 * 1280 + quad * 16) ^ swz;
    const int b0o = (l16 * 1280 + 64 + quad * 16) ^ swz;
    const int b1e = ((l16 + 16) * 1280 + quad * 16) ^ swz;
    const int b1o = ((l16 + 16) * 1280 + 64 + quad * 16) ^ swz;

    short8 xa0, xa1, xb0, xb1, ya0, ya1, yb0, yb1;
#define FLDA(P, s) \
    P##a0 = *(const short8*)(Ab + (((s) & 1) ? b0o : b0e) + ((s) >> 1) * 128); \
    P##a1 = *(const short8*)(Ab + (((s) & 1) ? b1o : b1e) + ((s) >> 1) * 128);
#define FLDB(P, s) \
    P##b0 = *(const short8*)(pB0 + (s) * 512); \
    P##b1 = *(const short8*)(pB1 + (s) * 512);
#define FLD(P, s) FLDA(P, s) FLDB(P, s)
#define FMM(P) \
    acc[0][0] = __builtin_amdgcn_mfma_f32_16x16x32_bf16(P##a0, P##b0, acc[0][0], 0, 0, 0); \
    acc[0][1] = __builtin_amdgcn_mfma_f32_16x16x32_bf16(P##a0, P##b1, acc[0][1], 0, 0, 0); \
    acc[1][0] = __builtin_amdgcn_mfma_f32_16x16x32_bf16(P##a1, P##b0, acc[1][0], 0, 0, 0); \
    acc[1][1] = __builtin_amdgcn_mfma_f32_16x16x32_bf16(P##a1, P##b1, acc[1][1], 0, 0, 0);

    // B loads are global (no LDS dependency): issue before the barrier
    FLDB(x, 0) FLDB(y, 1)
    __syncthreads();
    FLDA(x, 0) FLDA(y, 1)
    FMM(x) FLD(x, 2)
    FMM(y) FLD(y, 3)
    FMM(x) FLD(x, 4)
    FMM(y) FLD(y, 5)
    FMM(x) FLD(x, 6)
    FMM(y) FLD(y, 7)
    FMM(x) FLD(x, 8)
    FMM(y) FLD(y, 9)
    FMM(x) FLD(x, 10)
    FMM(y) FLD(y, 11)
    FMM(x) FLD(x, 12)
    FMM(y) FLD(y, 13)
    FMM(x) FLD(x, 14)
    FMM(y) FLD(y, 15)
    FMM(x) FLD(x, 16)
    FMM(y) FLD(y, 17)
    FMM(x) FLD(x, 18)
    FMM(y) FLD(y, 19)
    FMM(x)
    FMM(y)
#undef FLDA
#undef FLDB
#undef FLD
#undef FMM

    // ---- epilogue: o = (acc + bias)/deg, bf16 store, per-block BN partial stats
    float ssum[2] = {0.f, 0.f}, sssq[2] = {0.f, 0.f};
#pragma unroll
    for (int m = 0; m < 2; ++m) {
#pragma unroll
        for (int r = 0; r < 4; ++r) {
            const int row = n0 + m * 16 + quad * 4 + r;    // always < N_ENTS (3125*32 exact)
            const float rdeg = 1.0f / fmaxf((float)cnt[row], 1.0f);
#pragma unroll
            for (int n = 0; n < 2; ++n) {
                const int col = (2 * wave + n) * 16 + l16;
                const float o = (acc[m][n][r] + bf2f(bsl[col])) * rdeg;
                out[(size_t)row * DIM + col] = f2bf(o);
                ssum[n] += o;
                sssq[n] += o * o;
            }
        }
    }
#pragma unroll
    for (int n = 0; n < 2; ++n) {
        float s = ssum[n], q2 = sssq[n];
        s += __shfl_xor(s, 16, 64);  s += __shfl_xor(s, 32, 64);
        q2 += __shfl_xor(q2, 16, 64); q2 += __shfl_xor(q2, 32, 64);
        if (quad == 0) {
            const int col = (2 * wave + n) * 16 + l16;
            pstats[(size_t)blockIdx.x * 256 + col] = s;
            pstats[(size_t)blockIdx.x * 256 + 128 + col] = q2;
        }
    }
}

// ---------------- reduce per-block stats -> st[256] ----------------
__global__ __launch_bounds__(256) void k_stats(const float* __restrict__ pstats,
                                               float* __restrict__ st) {
    const int o = threadIdx.x;
    const int b0 = blockIdx.x * 25;                // grid 125: 125*25 = 3125 exact
    float s = 0.f;
    for (int b = b0; b < b0 + 25; ++b)
        s += pstats[(size_t)b * 256 + o];
    atomicAdd(&st[o], s);
}

// ---------------- fused scoring: one BLOCK per sample (4 waves x 16 negs) ----------------
// r12-proven: head/rel gathered once per wave, hr cached; 16 neg gathers issued
// back-to-back per wave (indices via coalesced negi load + shfl). 1024 blocks.
__global__ __launch_bounds__(256) void k_score(
    const int* __restrict__ head, const int* __restrict__ rel,
    const int* __restrict__ tail, const int* __restrict__ negi,
    const unsigned short* __restrict__ emb, const unsigned short* __restrict__ rtab,
    const float* __restrict__ st1, const unsigned short* __restrict__ gm1,
    const unsigned short* __restrict__ bt1,
    void* __restrict__ outp, const int* __restrict__ flag)
{
    const int wave = threadIdx.x >> 6, lane = threadIdx.x & 63;
    const int i = blockIdx.x;              // grid exact: BATCH
    const float inv_n = 1.0f / (float)N_ENTS;
    const int f0 = lane * 2, f1 = f0 + 1;
    const float mu0 = st1[f0] * inv_n, mu1 = st1[f1] * inv_n;
    const float va0 = st1[DIM + f0] * inv_n - mu0 * mu0;
    const float va1 = st1[DIM + f1] * inv_n - mu1 * mu1;
    const float g0 = bf2f(gm1[f0]) * rsqrtf(va0 + BN_EPS);
    const float g1 = bf2f(gm1[f1]) * rsqrtf(va1 + BN_EPS);
    const float o0 = bf2f(bt1[f0]) - mu0 * g0;
    const float o1 = bf2f(bt1[f1]) - mu1 * g1;
    const int isbf = flag[0];

    const uint* __restrict__ x32 = (const uint*)emb;
    // neg indices: one coalesced load; lane l holds negi[i*64+l]
    const int nIdx = negi[i * 64 + lane];
    const uint hv = x32[(size_t)head[i] * 64 + lane];
    const uint rv = ((const uint*)rtab)[(size_t)rel[i] * 64 + lane];
    const float hr0 = fmaxf(fmaf(bflo(hv), g0, o0), 0.f) + bflo(rv);
    const float hr1 = fmaxf(fmaf(bfhi(hv), g1, o1), 0.f) + bfhi(rv);

    auto score1 = [&](uint tvv, int oidx) {
        const float t0 = fmaxf(fmaf(bflo(tvv), g0, o0), 0.f);
        const float t1 = fmaxf(fmaf(bfhi(tvv), g1, o1), 0.f);
        const float d0 = hr0 - t0, d1 = hr1 - t1;
        float s = d0 * d0 + d1 * d1;
#pragma unroll
        for (int m = 32; m >= 1; m >>= 1) s += __shfl_xor(s, m, 64);
        if (lane == 0) {
            const float v = -sqrtf(s);
            if (isbf) ((unsigned short*)outp)[oidx] = f2bf(v);
            else      ((float*)outp)[oidx] = v;
        }
    };

    // wave w scores 16 negs; all 16 gathers issued before first use
    uint a[16];
#pragma unroll
    for (int k = 0; k < 16; ++k)
        a[k] = x32[(size_t)__shfl(nIdx, wave * 16 + k, 64) * 64 + lane];
    if (wave == 0) score1(x32[(size_t)tail[i] * 64 + lane], i);   // pos score
#pragma unroll
    for (int k = 0; k < 16; ++k)
        score1(a[k], BATCH + i * 64 + wave * 16 + k);
}

extern "C" void kernel_launch(void* const* d_in, const int* in_sizes, int n_in,
                              void* d_out, int out_size, void* d_ws, size_t ws_size,
                              hipStream_t stream)
{
    const int* head = (const int*)d_in[0];
    const int* rel  = (const int*)d_in[1];
    const int* tail = (const int*)d_in[2];
    const int* negi = (const int*)d_in[3];
    const int* eidx = (const int*)d_in[4];
    const int* etyp = (const int*)d_in[5];
    const void* ent_tab = d_in[6];
    const void* rtab_in = d_in[7];
    const void* bases_in = d_in[8];
    const void* coeffs_in = d_in[9];
    const void* wsl_in = d_in[10];
    const void* bsl_in = d_in[11];
    const void* gamma_in = d_in[12];
    const void* beta_in = d_in[13];

    char* ws = (char*)d_ws;
    size_t off = 0;
    auto alloc = [&](size_t bytes) -> char* {
        char* p = ws + off;
        off += (bytes + 511) & ~(size_t)511;
        return p;
    };
    int* flag            = (int*)alloc(4);
    int* cnt             = (int*)alloc((size_t)N_ENTS * 4);
    uint* bucket         = (uint*)alloc((size_t)N_ENTS * BCAP * 4);             // 25.6 MB
    unsigned short* xrow = (unsigned short*)alloc((size_t)N_ENTS * DIM * 2);    // fp32-input path only
    unsigned short* outA = (unsigned short*)alloc((size_t)N_ENTS * DIM * 2);    // layer-0 raw out
    unsigned short* outB = (unsigned short*)alloc((size_t)N_ENTS * DIM * 2);    // layer-1 raw out
    unsigned short* par  = (unsigned short*)alloc((size_t)P_TOTAL * 2);
    unsigned short* WtT  = (unsigned short*)alloc((size_t)2 * 81920 * 2);
    float* cf32          = (float*)alloc((size_t)2 * 17 * 4 * 4);
    float* pstats        = (float*)alloc((size_t)NBLK2 * 256 * 4);              // 3.2 MB
    float* stats         = (float*)alloc(2 * 2 * DIM * 4);
    (void)ws_size; (void)in_sizes; (void)n_in; (void)out_size;

    const int* esrc = eidx;
    const int* edst = eidx + NEDGE;

    // 8 dispatches: detect(+stats zero), conv(+WtT+cf32+cnt zero+params),
    // fillB, fused0, stats0, fused1, stats1, score.
    k_detect<<<1, 256, 0, stream>>>((const unsigned int*)ent_tab, flag, stats);

    k_conv<<<B_GRID, 256, 0, stream>>>(
        ent_tab, xrow, rtab_in, bases_in, coeffs_in, wsl_in, bsl_in, gamma_in, beta_in,
        par, WtT, cf32, cnt, flag);

    k_fillB<<<NEDGE / 256, 256, 0, stream>>>(esrc, edst, etyp, cnt, bucket);

    // layer 0 (no BN on input)
    k_fused<0><<<NBLK2, 256, 0, stream>>>(
        bucket, cnt, cf32, xrow, ent_tab, flag,
        stats, par + P_GAMMA, par + P_BETA,          // unused at LAY=0
        WtT, par + P_BSL, outA, pstats);
    k_stats<<<125, 256, 0, stream>>>(pstats, stats);

    // layer 1 (BN0+ReLU fused on the fly)
    k_fused<1><<<NBLK2, 256, 0, stream>>>(
        bucket, cnt, cf32 + 68, outA, ent_tab, flag,
        stats, par + P_GAMMA, par + P_BETA,
        WtT + 81920, par + P_BSL + DIM, outB, pstats);
    k_stats<<<125, 256, 0, stream>>>(pstats, stats + 2 * DIM);

    k_score<<<BATCH, 256, 0, stream>>>(
        head, rel, tail, negi, outB, par + P_REL,
        stats + 2 * DIM, par + P_GAMMA + DIM, par + P_BETA + DIM,
        d_out, flag);
}

// Round 16
// 300.293 us; speedup vs baseline: 1.2935x; 1.0169x over previous
//
#include <hip/hip_runtime.h>
#include <stdint.h>

// Problem constants
#define N_ENTS  100000
#define N_RELS  16
#define DIM     128
#define NB      4
#define TILE_U  10240           // ushorts per WtT n-tile: 80*16*8
#define NEDGE   640000
#define BATCH   1024
#define NNEG    64
#define BN_EPS  1e-5f
#define BCAP    64              // bucket capacity per node
#define SENTR   0x01000000u     // sentinel record: rel=16 (zero coeff), src=0
#define NPB     32              // nodes per fused block
#define NBLK2   3125            // N_ENTS/NPB exact

// merged k_conv block ranges
#define B_X     0               // [0,6250): x fp32->bf16 (early-exit if bf16)
#define B_CNT   6250            // [6250,6348): zero cnt (98 blocks of uint4)
#define B_TW    6348            // [6348,6428): WtT build from RAW inputs (80 blocks)
#define B_CF    6428            // cf32 table (1 block)
#define B_PAR   6429            // [6429,6440): small param convert (2816 elems)
#define B_GRID  6440

// converted-parameter buffer layout (ushort offsets) — only small params now
#define P_REL    0        // [16][128]
#define P_BSL    2048     // [2][128]
#define P_GAMMA  2304     // [2][128]
#define P_BETA   2560     // [2][128]
#define P_TOTAL  2816

typedef unsigned int uint;
typedef short short8 __attribute__((ext_vector_type(8)));
typedef float f4 __attribute__((ext_vector_type(4)));
typedef float f2 __attribute__((ext_vector_type(2)));
typedef float f4v __attribute__((ext_vector_type(4)));

// packed dual-FP32 FMA (CDNA2+). op_sel broadcast lets ONE float2 coeff pair feed
// both packed lanes: _LO uses c.lo for both halves, _HI uses c.hi for both halves.
#define PKFMA(D, A, B, C) \
    asm("v_pk_fma_f32 %0, %1, %2, %3" : "=v"(D) : "v"(A), "v"(B), "v"(C))
#define PKFMA_LO(ACC, C, X) \
    asm("v_pk_fma_f32 %0, %1, %2, %0 op_sel:[0,0,0] op_sel_hi:[0,1,1]" \
        : "+v"(ACC) : "v"(C), "v"(X))
#define PKFMA_HI(ACC, C, X) \
    asm("v_pk_fma_f32 %0, %1, %2, %0 op_sel:[1,0,0] op_sel_hi:[1,1,1]" \
        : "+v"(ACC) : "v"(C), "v"(X))

__device__ __forceinline__ float bf2f(unsigned short u) {
    return __uint_as_float(((unsigned int)u) << 16);
}
__device__ __forceinline__ float bflo(unsigned int u) { return __uint_as_float(u << 16); }
__device__ __forceinline__ float bfhi(unsigned int u) { return __uint_as_float(u & 0xffff0000u); }
__device__ __forceinline__ unsigned short f2bf(float f) {
    unsigned int x = __float_as_uint(f);
    x += 0x7fffu + ((x >> 16) & 1u);
    return (unsigned short)(x >> 16);
}
__device__ __forceinline__ unsigned int pack2(float a, float b) {
    return (unsigned int)f2bf(a) | ((unsigned int)f2bf(b) << 16);
}

// ---------------- dtype detection (fp32 vs bf16 storage) + stats zero ----------------
__device__ __forceinline__ int bf16_like(unsigned int h) {
    unsigned int m = h & 0x7FFFu;
    return (m == 0u) || (m >= 0x2D00u && m < 0x4400u);
}
__global__ __launch_bounds__(256) void k_detect(const unsigned int* __restrict__ ent,
                                                int* __restrict__ flag,
                                                float* __restrict__ stats) {
    __shared__ int cnt[256];
    unsigned int u = ent[threadIdx.x];
    cnt[threadIdx.x] = bf16_like(u & 0xFFFFu) & bf16_like(u >> 16);
    stats[threadIdx.x] = 0.f;                      // zero stats[512] inline
    stats[256 + threadIdx.x] = 0.f;
    __syncthreads();
    for (int s = 128; s > 0; s >>= 1) {
        if (threadIdx.x < s) cnt[threadIdx.x] += cnt[threadIdx.x + s];
        __syncthreads();
    }
    if (threadIdx.x == 0) flag[0] = (cnt[0] >= 140) ? 1 : 0;
}

// ---------------- merged convert/setup kernel ----------------
// x convert (fp32 path), cnt zero, WtT build (from raw inputs), cf32, small params.
__device__ __forceinline__ unsigned short cvt1(const void* src, int i, int isbf) {
    return isbf ? ((const unsigned short*)src)[i] : f2bf(((const float*)src)[i]);
}
__global__ __launch_bounds__(256) void k_conv(
    const void* __restrict__ src, unsigned short* __restrict__ xrow,
    const void* __restrict__ rtab, const void* __restrict__ bases,
    const void* __restrict__ coeffs, const void* __restrict__ wsl,
    const void* __restrict__ bsl, const void* __restrict__ gamma,
    const void* __restrict__ beta,
    unsigned short* __restrict__ par, unsigned short* __restrict__ WtT,
    float* __restrict__ cf32, int* __restrict__ cnt, const int* __restrict__ flag)
{
    const int b = blockIdx.x;
    const int isbf = flag[0];
    if (b < B_CNT) {                               // ---- x conversion
        if (isbf) return;                          // bf16 input: ent used directly
        const int kc = threadIdx.x >> 4, r = threadIdx.x & 15;
        const int n = b * 16 + r;
        const size_t e0 = (size_t)n * DIM + kc * 8;
        const float4 f0 = *(const float4*)((const float*)src + e0);
        const float4 f1 = *(const float4*)((const float*)src + e0 + 4);
        uint4 w;
        w.x = pack2(f0.x, f0.y); w.y = pack2(f0.z, f0.w);
        w.z = pack2(f1.x, f1.y); w.w = pack2(f1.z, f1.w);
        *(uint4*)(xrow + e0) = w;
        return;
    }
    if (b < B_TW) {                                // ---- zero cnt via uint4 stores
        const int i = (b - B_CNT) * 256 + threadIdx.x;   // uint4 index
        if (i < N_ENTS / 4) {
            uint4 z = {0, 0, 0, 0};
            ((uint4*)cnt)[i] = z;
        }
        return;
    }
    if (b < B_CF) {                                // ---- WtT from RAW wsl/bases
        const int i = (b - B_TW) * 256 + threadIdx.x;    // [0, 20480)
        const int l = i / 10240;
        const int rem = i - l * 10240;
        const int jt2 = rem / 1280;
        const int rem2 = rem - jt2 * 1280;
        const int kc = rem2 >> 4, r = rem2 & 15;
        const int n = jt2 * 16 + r;
        unsigned short v[8];
#pragma unroll
        for (int e = 0; e < 8; ++e) {
            const int k = kc * 8 + e;
            v[e] = (k < DIM)
                ? cvt1(wsl,   l * DIM * DIM + k * DIM + n, isbf)
                : cvt1(bases, l * NB * DIM * DIM + (k - DIM) * DIM + n, isbf);
        }
        *(uint4*)(WtT + (size_t)l * 81920 + (size_t)jt2 * TILE_U + (size_t)kc * 128 + r * 8) = *(uint4*)v;
        return;
    }
    if (b == B_CF) {                               // ---- cf32 [2][17][4], rel=16 -> 0
        const int i = threadIdx.x;
        if (i < 2 * 17 * 4) {
            const int l = i / 68, rem = i - l * 68, r = rem >> 2, bb = rem & 3;
            const int idx = l * N_RELS * NB + r * NB + bb;
            cf32[i] = (r < N_RELS)
                ? (isbf ? bf2f(((const unsigned short*)coeffs)[idx])
                        : ((const float*)coeffs)[idx])
                : 0.f;
        }
        return;
    }
    // ---- small params: rel, bsl, gamma, beta
    const int i = (b - B_PAR) * 256 + threadIdx.x;
    if (i >= P_TOTAL) return;
    unsigned short v;
    if      (i < P_BSL)    v = cvt1(rtab,  i - P_REL,   isbf);
    else if (i < P_GAMMA)  v = cvt1(bsl,   i - P_BSL,   isbf);
    else if (i < P_BETA)   v = cvt1(gamma, i - P_GAMMA, isbf);
    else                   v = cvt1(beta,  i - P_BETA,  isbf);
    par[i] = v;
}

// ---------------- one-kernel bucket CSR: cnt + bucket[n][64] ----------------
__global__ __launch_bounds__(256) void k_fillB(const int* __restrict__ src, const int* __restrict__ dst,
                                               const int* __restrict__ et, int* __restrict__ cnt,
                                               uint* __restrict__ bucket) {
    const int e = blockIdx.x * 256 + threadIdx.x;   // grid exact: NEDGE/256
    const int d = dst[e];
    const int p = atomicAdd(&cnt[d], 1);
    if (p < BCAP) bucket[(size_t)d * BCAP + p] = (uint)src[e] | ((uint)et[e] << 20);
}

// ---------------- FUSED (BN of prev layer) + aggregate + GEMM + epilogue ----------------
// r15-proven structure + r16: (a) PRE-MASKED stash (sentinels written in phase 0, per
// node once — first-8 and j=1 paths fully unconditional); (b) packed v_pk_fma_f32 with
// op_sel coefficient broadcast — 16 scalar FMA -> 4 pk_fma per record, same 1x b128
// cc read. Per-record VALU ~22 -> ~8.
// DO NOT: register ping-pong pipelining (r7/r11), atomic stats (r8). Measured.
template<int LAY>
__global__ __launch_bounds__(256, 4) void k_fused(
    const uint* __restrict__ bucket, const int* __restrict__ cnt,
    const float* __restrict__ cf, const unsigned short* __restrict__ xin,
    const void* __restrict__ ent, const int* __restrict__ flag,
    const float* __restrict__ stp, const unsigned short* __restrict__ gprev,
    const unsigned short* __restrict__ bprev,
    const unsigned short* __restrict__ wtT, const unsigned short* __restrict__ bsl,
    unsigned short* __restrict__ out, float* __restrict__ pstats)
{
    __shared__ unsigned short Ash[NPB * 640];            // 40960 B exactly
    const int tid = threadIdx.x;
    const int wave = tid >> 6, lane = tid & 63;
    const int n0 = blockIdx.x * NPB;
    const float inv_n = 1.0f / (float)N_ENTS;

    const unsigned short* __restrict__ xs =
        (LAY == 0 && flag[0]) ? (const unsigned short*)ent : xin;
    const int mybase = n0 + wave * 8;
    char* AshB = (char*)Ash;
    const int cfb = (wave * 8 + 7) * 1280 + 512;         // per-wave cf stash base

    // hoisted wave-uniform degree loads (s_load) — used for tail bounds + epilogue
    int cns[8];
#pragma unroll
    for (int k = 0; k < 8; ++k) cns[k] = cnt[mybase + k];

    // ---- phase 0: stash bucket records (16/node, PRE-MASKED) + cf table inside Ash
    {
        const int nd = wave * 8 + (lane >> 3);           // this wave's nodes only
        const int p  = lane & 7;                         // record pair 0..7 (recs 0..15)
        const int cnd = cnt[n0 + nd];                    // raw degree of this node
        uint2 rv = *(const uint2*)(bucket + (size_t)(n0 + nd) * BCAP + p * 2);
        if (p * 2     >= cnd) rv.x = SENTR;              // sentinel: rel=16, src=0
        if (p * 2 + 1 >= cnd) rv.y = SENTR;
        *(uint2*)(AshB + nd * 1280 + 256 + p * 8) = rv;
        if (lane < 17) {
            const float4 c4 = *(const float4*)(cf + lane * 4);
            *(float4*)(AshB + cfb + lane * 16) = c4;
        }
    }

    // per-lane BN coeffs for gather columns {2*lane, 2*lane+1} (layer 1 only)
    f2 gn2, of2;
    gn2.x = 1.f; gn2.y = 1.f; of2.x = 0.f; of2.y = 0.f;
    if (LAY) {
        const int f0 = lane * 2, f1 = f0 + 1;
        const float mu0 = stp[f0] * inv_n, mu1 = stp[f1] * inv_n;
        const float va0 = stp[DIM + f0] * inv_n - mu0 * mu0;
        const float va1 = stp[DIM + f1] * inv_n - mu1 * mu1;
        gn2.x = bf2f(gprev[f0]) * rsqrtf(va0 + BN_EPS); of2.x = bf2f(bprev[f0]) - mu0 * gn2.x;
        gn2.y = bf2f(gprev[f1]) * rsqrtf(va1 + BN_EPS); of2.y = bf2f(bprev[f1]) - mu1 * gn2.y;
    }

    // ---- phase 1: stage self rows into LDS (k 0..127 = 256B/row), swizzled, BN-applied
    {
        const int r = tid >> 3, c = tid & 7;       // 32 rows; chunks c and c+8 (16B each)
        const size_t e0 = (size_t)(n0 + r) * DIM + c * 8;
        uint4 v0 = *(const uint4*)(xs + e0);
        uint4 v1 = *(const uint4*)(xs + e0 + 64);
        if (LAY) {
            uint vv[8] = {v0.x, v0.y, v0.z, v0.w, v1.x, v1.y, v1.z, v1.w};
#pragma unroll
            for (int p = 0; p < 8; ++p) {
                const int f0 = c * 8 + (p >> 2) * 64 + (p & 3) * 2;
                const float mu0 = stp[f0] * inv_n, mu1 = stp[f0 + 1] * inv_n;
                const float va0 = stp[DIM + f0] * inv_n - mu0 * mu0;
                const float va1 = stp[DIM + f0 + 1] * inv_n - mu1 * mu1;
                const float g0 = bf2f(gprev[f0]) * rsqrtf(va0 + BN_EPS);
                const float g1 = bf2f(gprev[f0 + 1]) * rsqrtf(va1 + BN_EPS);
                const float o0 = bf2f(bprev[f0]) - mu0 * g0;
                const float o1 = bf2f(bprev[f0 + 1]) - mu1 * g1;
                const float w0 = fmaxf(fmaf(bflo(vv[p]), g0, o0), 0.f);
                const float w1 = fmaxf(fmaf(bfhi(vv[p]), g1, o1), 0.f);
                vv[p] = pack2(w0, w1);
            }
            v0.x = vv[0]; v0.y = vv[1]; v0.z = vv[2]; v0.w = vv[3];
            v1.x = vv[4]; v1.y = vv[5]; v1.z = vv[6]; v1.w = vv[7];
        }
        const int byte0 = (r * 1280 + c * 16) ^ ((r & 7) << 4);
        *(uint4*)(AshB + byte0) = v0;
        *(uint4*)(AshB + byte0 + 128) = v1;   // +128: bit7 only, outside XOR bits 4-6
    }

    // ---- phase 2: gather-aggregate; unconditional pre-masked first-8, pk-FMA core
    const uint* __restrict__ x32 = (const uint*)xs;
    for (int pr = 0; pr < 4; ++pr) {
        const int la = wave * 8 + pr * 2;
        const int na = mybase + pr * 2;
        int ca = cns[pr * 2];     if (ca > BCAP) ca = BCAP;
        int cb = cns[pr * 2 + 1]; if (cb > BCAP) cb = BCAP;
        f2 acc2[2][NB];
#pragma unroll
        for (int h = 0; h < 2; ++h)
#pragma unroll
            for (int b = 0; b < NB; ++b) { acc2[h][b].x = 0.f; acc2[h][b].y = 0.f; }

        // first 8 records of BOTH nodes: fully unconditional (stash pre-masked)
        uint rec[2][8], xw[2][8];
#pragma unroll
        for (int h = 0; h < 2; ++h) {
#pragma unroll
            for (int s = 0; s < 8; ++s) {
                const uint rr = *(const uint*)(AshB + (la + h) * 1280 + 256 + s * 4);
                rec[h][s] = rr;
                xw[h][s] = x32[(size_t)(rr & 0xFFFFFu) * 64 + lane];
            }
        }
#pragma unroll
        for (int h = 0; h < 2; ++h) {
#pragma unroll
            for (int s = 0; s < 8; ++s) {
                const int rel = (int)(rec[h][s] >> 20);   // 16 -> zero coeffs
                const f4v cc = *(const f4v*)(AshB + cfb + rel * 16);  // broadcast
                const f2 cLo = __builtin_shufflevector(cc, cc, 0, 1);
                const f2 cHi = __builtin_shufflevector(cc, cc, 2, 3);
                f2 x2;
                if (LAY) {
                    f2 raw2; raw2.x = bflo(xw[h][s]); raw2.y = bfhi(xw[h][s]);
                    f2 t; PKFMA(t, raw2, gn2, of2);
                    x2.x = fmaxf(t.x, 0.f); x2.y = fmaxf(t.y, 0.f);
                } else {
                    x2.x = bflo(xw[h][s]); x2.y = bfhi(xw[h][s]);
                }
                PKFMA_LO(acc2[h][0], cLo, x2);
                PKFMA_HI(acc2[h][1], cLo, x2);
                PKFMA_LO(acc2[h][2], cHi, x2);
                PKFMA_HI(acc2[h][3], cHi, x2);
            }
        }
        // tail (deg>8, P~19%): j=1 from pre-masked stash (no mask), j>=2 global (mask)
#pragma unroll
        for (int h = 0; h < 2; ++h) {
            const int cn = h ? cb : ca;
            const uint4* __restrict__ bkg = (const uint4*)(bucket + (size_t)(na + h) * BCAP);
            for (int j = 1; j * 8 < cn; ++j) {
                const int b8 = j * 8;
                uint trec[8], txw[8];
                if (j < 2) {
#pragma unroll
                    for (int s = 0; s < 8; ++s)
                        trec[s] = *(const uint*)(AshB + (la + h) * 1280 + 256 + (b8 + s) * 4);
#pragma unroll
                    for (int s = 0; s < 8; ++s)
                        txw[s] = x32[(size_t)(trec[s] & 0xFFFFFu) * 64 + lane];
                } else {
                    const uint4 r0 = bkg[j * 2];
                    const uint4 r1 = bkg[j * 2 + 1];
                    trec[0] = r0.x; trec[1] = r0.y; trec[2] = r0.z; trec[3] = r0.w;
                    trec[4] = r1.x; trec[5] = r1.y; trec[6] = r1.z; trec[7] = r1.w;
#pragma unroll
                    for (int s = 0; s < 8; ++s) {
                        uint rr = trec[s];
                        if (b8 + s >= cn) rr = SENTR;
                        trec[s] = rr;
                        txw[s] = x32[(size_t)(rr & 0xFFFFFu) * 64 + lane];
                    }
                }
#pragma unroll
                for (int s = 0; s < 8; ++s) {
                    const int rel = (int)(trec[s] >> 20);
                    const f4v cc = *(const f4v*)(AshB + cfb + rel * 16);
                    const f2 cLo = __builtin_shufflevector(cc, cc, 0, 1);
                    const f2 cHi = __builtin_shufflevector(cc, cc, 2, 3);
                    f2 x2;
                    if (LAY) {
                        f2 raw2; raw2.x = bflo(txw[s]); raw2.y = bfhi(txw[s]);
                        f2 t; PKFMA(t, raw2, gn2, of2);
                        x2.x = fmaxf(t.x, 0.f); x2.y = fmaxf(t.y, 0.f);
                    } else {
                        x2.x = bflo(txw[s]); x2.y = bfhi(txw[s]);
                    }
                    PKFMA_LO(acc2[h][0], cLo, x2);
                    PKFMA_HI(acc2[h][1], cLo, x2);
                    PKFMA_LO(acc2[h][2], cHi, x2);
                    PKFMA_HI(acc2[h][3], cHi, x2);
                }
            }
        }
        // aggregate write AFTER this pr's records consumed (overwrites record stash;
        // pr=3's write overwrites the cf stash — nothing reads either afterwards)
#pragma unroll
        for (int h = 0; h < 2; ++h) {
            const int ra = wave * 8 + pr * 2 + h;
            const int swz = (ra & 7) << 4;
#pragma unroll
            for (int b = 0; b < NB; ++b) {
                // A[ra][128 + b*128 + 2*lane .. +1]  (bank-conflict-free: lane*4 stride)
                const int byte = (ra * 1280 + 256 + b * 256 + lane * 4) ^ swz;
                *(uint*)(AshB + byte) = pack2(acc2[h][b].x, acc2[h][b].y);
            }
        }
    }

    // ---- phase 3: MFMA. wave w: m-tiles {0,1} x n-tiles {2w,2w+1}, K=640 (20 steps)
    const int quad = lane >> 4, l16 = lane & 15;
    f4 acc[2][2];
#pragma unroll
    for (int i = 0; i < 2; ++i)
#pragma unroll
        for (int j = 0; j < 2; ++j)
#pragma unroll
            for (int r = 0; r < 4; ++r) acc[i][j][r] = 0.f;

    const unsigned short* __restrict__ pB0 = wtT + (size_t)(2 * wave) * TILE_U + quad * 128 + l16 * 8;
    const unsigned short* __restrict__ pB1 = pB0 + TILE_U;
    const char* Ab = (const char*)Ash;
    const int swz = (l16 & 7) << 4;
    // even/odd ks bases: XOR touches bits 4-6 and ks*64 carries bit 6 -> two bases
    const int b0e = (l16 * 1280 + quad * 16) ^ swz;
    const int b0o = (l16 * 1280 + 64 + quad * 16) ^ swz;
    const int b1e = ((l16 + 16) * 1280 + quad * 16) ^ swz;
    const int b1o = ((l16 + 16) * 1280 + 64 + quad * 16) ^ swz;

    short8 xa0, xa1, xb0, xb1, ya0, ya1, yb0, yb1;
#define FLDA(P, s) \
    P##a0 = *(const short8*)(Ab + (((s) & 1) ? b0o : b0e) + ((s) >> 1) * 128); \
    P##a1 = *(const short8*)(Ab + (((s) & 1) ? b1o : b1e) + ((s) >> 1) * 128);
#define FLDB(P, s) \
    P##b0 = *(const short8*)(pB0 + (s) * 512); \
    P##b1 = *(const short8*)(pB1 + (s) * 512);
#define FLD(P, s) FLDA(P, s) FLDB(P, s)
#define FMM(P) \
    acc[0][0] = __builtin_amdgcn_mfma_f32_16x16x32_bf16(P##a0, P##b0, acc[0][0], 0, 0, 0); \
    acc[0][1] = __builtin_amdgcn_mfma_f32_16x16x32_bf16(P##a0, P##b1, acc[0][1], 0, 0, 0); \
    acc[1][0] = __builtin_amdgcn_mfma_f32_16x16x32_bf16(P##a1, P##b0, acc[1][0], 0, 0, 0); \
    acc[1][1] = __builtin_amdgcn_mfma_f32_16x16x32_bf16(P##a1, P##b1, acc[1][1], 0, 0, 0);

    // B loads are global (no LDS dependency): issue before the barrier
    FLDB(x, 0) FLDB(y, 1)
    __syncthreads();
    FLDA(x, 0) FLDA(y, 1)
    FMM(x) FLD(x, 2)
    FMM(y) FLD(y, 3)
    FMM(x) FLD(x, 4)
    FMM(y) FLD(y, 5)
    FMM(x) FLD(x, 6)
    FMM(y) FLD(y, 7)
    FMM(x) FLD(x, 8)
    FMM(y) FLD(y, 9)
    FMM(x) FLD(x, 10)
    FMM(y) FLD(y, 11)
    FMM(x) FLD(x, 12)
    FMM(y) FLD(y, 13)
    FMM(x) FLD(x, 14)
    FMM(y) FLD(y, 15)
    FMM(x) FLD(x, 16)
    FMM(y) FLD(y, 17)
    FMM(x) FLD(x, 18)
    FMM(y) FLD(y, 19)
    FMM(x)
    FMM(y)
#undef FLDA
#undef FLDB
#undef FLD
#undef FMM

    // ---- epilogue: o = (acc + bias)/deg, bf16 store, per-block BN partial stats
    float ssum[2] = {0.f, 0.f}, sssq[2] = {0.f, 0.f};
#pragma unroll
    for (int m = 0; m < 2; ++m) {
#pragma unroll
        for (int r = 0; r < 4; ++r) {
            const int row = n0 + m * 16 + quad * 4 + r;    // always < N_ENTS (3125*32 exact)
            const float rdeg = 1.0f / fmaxf((float)cnt[row], 1.0f);
#pragma unroll
            for (int n = 0; n < 2; ++n) {
                const int col = (2 * wave + n) * 16 + l16;
                const float o = (acc[m][n][r] + bf2f(bsl[col])) * rdeg;
                out[(size_t)row * DIM + col] = f2bf(o);
                ssum[n] += o;
                sssq[n] += o * o;
            }
        }
    }
#pragma unroll
    for (int n = 0; n < 2; ++n) {
        float s = ssum[n], q2 = sssq[n];
        s += __shfl_xor(s, 16, 64);  s += __shfl_xor(s, 32, 64);
        q2 += __shfl_xor(q2, 16, 64); q2 += __shfl_xor(q2, 32, 64);
        if (quad == 0) {
            const int col = (2 * wave + n) * 16 + l16;
            pstats[(size_t)blockIdx.x * 256 + col] = s;
            pstats[(size_t)blockIdx.x * 256 + 128 + col] = q2;
        }
    }
}

// ---------------- reduce per-block stats -> st[256] ----------------
__global__ __launch_bounds__(256) void k_stats(const float* __restrict__ pstats,
                                               float* __restrict__ st) {
    const int o = threadIdx.x;
    const int b0 = blockIdx.x * 25;                // grid 125: 125*25 = 3125 exact
    float s = 0.f;
    for (int b = b0; b < b0 + 25; ++b)
        s += pstats[(size_t)b * 256 + o];
    atomicAdd(&st[o], s);
}

// ---------------- fused scoring: one BLOCK per sample (4 waves x 16 negs) ----------------
// r12-proven: head/rel gathered once per wave, hr cached; 16 neg gathers issued
// back-to-back per wave (indices via coalesced negi load + shfl). 1024 blocks.
__global__ __launch_bounds__(256) void k_score(
    const int* __restrict__ head, const int* __restrict__ rel,
    const int* __restrict__ tail, const int* __restrict__ negi,
    const unsigned short* __restrict__ emb, const unsigned short* __restrict__ rtab,
    const float* __restrict__ st1, const unsigned short* __restrict__ gm1,
    const unsigned short* __restrict__ bt1,
    void* __restrict__ outp, const int* __restrict__ flag)
{
    const int wave = threadIdx.x >> 6, lane = threadIdx.x & 63;
    const int i = blockIdx.x;              // grid exact: BATCH
    const float inv_n = 1.0f / (float)N_ENTS;
    const int f0 = lane * 2, f1 = f0 + 1;
    const float mu0 = st1[f0] * inv_n, mu1 = st1[f1] * inv_n;
    const float va0 = st1[DIM + f0] * inv_n - mu0 * mu0;
    const float va1 = st1[DIM + f1] * inv_n - mu1 * mu1;
    const float g0 = bf2f(gm1[f0]) * rsqrtf(va0 + BN_EPS);
    const float g1 = bf2f(gm1[f1]) * rsqrtf(va1 + BN_EPS);
    const float o0 = bf2f(bt1[f0]) - mu0 * g0;
    const float o1 = bf2f(bt1[f1]) - mu1 * g1;
    const int isbf = flag[0];

    const uint* __restrict__ x32 = (const uint*)emb;
    // neg indices: one coalesced load; lane l holds negi[i*64+l]
    const int nIdx = negi[i * 64 + lane];
    const uint hv = x32[(size_t)head[i] * 64 + lane];
    const uint rv = ((const uint*)rtab)[(size_t)rel[i] * 64 + lane];
    const float hr0 = fmaxf(fmaf(bflo(hv), g0, o0), 0.f) + bflo(rv);
    const float hr1 = fmaxf(fmaf(bfhi(hv), g1, o1), 0.f) + bfhi(rv);

    auto score1 = [&](uint tvv, int oidx) {
        const float t0 = fmaxf(fmaf(bflo(tvv), g0, o0), 0.f);
        const float t1 = fmaxf(fmaf(bfhi(tvv), g1, o1), 0.f);
        const float d0 = hr0 - t0, d1 = hr1 - t1;
        float s = d0 * d0 + d1 * d1;
#pragma unroll
        for (int m = 32; m >= 1; m >>= 1) s += __shfl_xor(s, m, 64);
        if (lane == 0) {
            const float v = -sqrtf(s);
            if (isbf) ((unsigned short*)outp)[oidx] = f2bf(v);
            else      ((float*)outp)[oidx] = v;
        }
    };

    // wave w scores 16 negs; all 16 gathers issued before first use
    uint a[16];
#pragma unroll
    for (int k = 0; k < 16; ++k)
        a[k] = x32[(size_t)__shfl(nIdx, wave * 16 + k, 64) * 64 + lane];
    if (wave == 0) score1(x32[(size_t)tail[i] * 64 + lane], i);   // pos score
#pragma unroll
    for (int k = 0; k < 16; ++k)
        score1(a[k], BATCH + i * 64 + wave * 16 + k);
}

extern "C" void kernel_launch(void* const* d_in, const int* in_sizes, int n_in,
                              void* d_out, int out_size, void* d_ws, size_t ws_size,
                              hipStream_t stream)
{
    const int* head = (const int*)d_in[0];
    const int* rel  = (const int*)d_in[1];
    const int* tail = (const int*)d_in[2];
    const int* negi = (const int*)d_in[3];
    const int* eidx = (const int*)d_in[4];
    const int* etyp = (const int*)d_in[5];
    const void* ent_tab = d_in[6];
    const void* rtab_in = d_in[7];
    const void* bases_in = d_in[8];
    const void* coeffs_in = d_in[9];
    const void* wsl_in = d_in[10];
    const void* bsl_in = d_in[11];
    const void* gamma_in = d_in[12];
    const void* beta_in = d_in[13];

    char* ws = (char*)d_ws;
    size_t off = 0;
    auto alloc = [&](size_t bytes) -> char* {
        char* p = ws + off;
        off += (bytes + 511) & ~(size_t)511;
        return p;
    };
    int* flag            = (int*)alloc(4);
    int* cnt             = (int*)alloc((size_t)N_ENTS * 4);
    uint* bucket         = (uint*)alloc((size_t)N_ENTS * BCAP * 4);             // 25.6 MB
    unsigned short* xrow = (unsigned short*)alloc((size_t)N_ENTS * DIM * 2);    // fp32-input path only
    unsigned short* outA = (unsigned short*)alloc((size_t)N_ENTS * DIM * 2);    // layer-0 raw out
    unsigned short* outB = (unsigned short*)alloc((size_t)N_ENTS * DIM * 2);    // layer-1 raw out
    unsigned short* par  = (unsigned short*)alloc((size_t)P_TOTAL * 2);
    unsigned short* WtT  = (unsigned short*)alloc((size_t)2 * 81920 * 2);
    float* cf32          = (float*)alloc((size_t)2 * 17 * 4 * 4);
    float* pstats        = (float*)alloc((size_t)NBLK2 * 256 * 4);              // 3.2 MB
    float* stats         = (float*)alloc(2 * 2 * DIM * 4);
    (void)ws_size; (void)in_sizes; (void)n_in; (void)out_size;

    const int* esrc = eidx;
    const int* edst = eidx + NEDGE;

    // 8 dispatches: detect(+stats zero), conv(+WtT+cf32+cnt zero+params),
    // fillB, fused0, stats0, fused1, stats1, score.
    k_detect<<<1, 256, 0, stream>>>((const unsigned int*)ent_tab, flag, stats);

    k_conv<<<B_GRID, 256, 0, stream>>>(
        ent_tab, xrow, rtab_in, bases_in, coeffs_in, wsl_in, bsl_in, gamma_in, beta_in,
        par, WtT, cf32, cnt, flag);

    k_fillB<<<NEDGE / 256, 256, 0, stream>>>(esrc, edst, etyp, cnt, bucket);

    // layer 0 (no BN on input)
    k_fused<0><<<NBLK2, 256, 0, stream>>>(
        bucket, cnt, cf32, xrow, ent_tab, flag,
        stats, par + P_GAMMA, par + P_BETA,          // unused at LAY=0
        WtT, par + P_BSL, outA, pstats);
    k_stats<<<125, 256, 0, stream>>>(pstats, stats);

    // layer 1 (BN0+ReLU fused on the fly)
    k_fused<1><<<NBLK2, 256, 0, stream>>>(
        bucket, cnt, cf32 + 68, outA, ent_tab, flag,
        stats, par + P_GAMMA, par + P_BETA,
        WtT + 81920, par + P_BSL + DIM, outB, pstats);
    k_stats<<<125, 256, 0, stream>>>(pstats, stats + 2 * DIM);

    k_score<<<BATCH, 256, 0, stream>>>(
        head, rel, tail, negi, outB, par + P_REL,
        stats + 2 * DIM, par + P_GAMMA + DIM, par + P_BETA + DIM,
        d_out, flag);
}